// Round 4
// baseline (450.165 us; speedup 1.0000x reference)
//
#include <hip/hip_runtime.h>
#include <hip/hip_bf16.h>
#include <math.h>

namespace {
constexpr int Bb = 256, Jj = 21, Cc = 256, Hh = 8, Dd = 256;
constexpr int Mrows = Bb * Jj;      // 5376
constexpr int HD    = Hh * Dd;      // 2048
constexpr int QKVN  = 3 * HD;       // 6144
constexpr int KNN   = 8;
constexpr int KFUSE = HD + Cc + Cc; // 2560

// ---- workspace byte offsets (all 256-aligned) ----
constexpr size_t OFF_QKV   = 0;                                   // bf16 5376x6144
constexpr size_t OFF_ATT   = OFF_QKV   + (size_t)Mrows*QKVN*2;    // bf16 5376x2048
constexpr size_t OFF_T     = OFF_ATT   + (size_t)Mrows*HD*2;      // f32  5376x2048
constexpr size_t OFF_G     = OFF_T     + (size_t)Mrows*HD*4;      // f32  256x2048
constexpr size_t OFF_JFB   = OFF_G     + (size_t)Cc*HD*4;         // bf16 5376x256
constexpr size_t OFF_H1B   = OFF_JFB   + (size_t)Mrows*Cc*2;      // bf16 5376x256
constexpr size_t OFF_H2F   = OFF_H1B   + (size_t)Mrows*Cc*2;      // f32  5376x256
constexpr size_t OFF_WQKVT = OFF_H2F   + (size_t)Mrows*Cc*4;      // bf16 2x6144x256
constexpr size_t OFF_FBT   = OFF_WQKVT + (size_t)2*QKVN*Cc*2;     // bf16 2x256x2560
constexpr size_t OFF_WVP   = OFF_FBT   + (size_t)2*Cc*KFUSE*2;    // f32  256x24
constexpr size_t OFF_VPROJ = OFF_WVP   + (size_t)Hh*Cc*3*4;       // f32  5376x24
constexpr size_t OFF_CRD   = OFF_VPROJ + (size_t)Mrows*24*4;      // f32  5376x3
constexpr size_t OFF_NBR0  = OFF_CRD   + (size_t)Mrows*3*4 + 160; // int  5376x8
constexpr size_t OFF_NBR1  = OFF_NBR0  + (size_t)Mrows*KNN*4;
constexpr size_t OFF_STAT  = OFF_NBR1  + (size_t)Mrows*KNN*4;     // 2 f32
} // namespace

typedef short short8 __attribute__((ext_vector_type(8)));
typedef unsigned short u16x8 __attribute__((ext_vector_type(8)));
typedef float f32x4 __attribute__((ext_vector_type(4)));

__device__ __forceinline__ unsigned short f2bf(float x) {
    unsigned int u = __float_as_uint(x);
    u = u + 0x7fffu + ((u >> 16) & 1u);            // round-to-nearest-even
    return (unsigned short)(u >> 16);
}
__device__ __forceinline__ float bf2f(unsigned short b) {
    return __uint_as_float(((unsigned int)b) << 16);
}

// ---------------------------------------------------------------------------
// exact stable-argsort kNN: ranks 1..8 by (d2, index) ascending
__global__ __launch_bounds__(64)
void knn_kernel(const float* __restrict__ src, int ld, int* __restrict__ nbr) {
    int b = blockIdx.x;
    __shared__ float cs[Jj][3];
    int t = threadIdx.x;
    if (t < Jj) {
        const float* p = src + (size_t)(b * Jj + t) * ld;
        cs[t][0] = p[0]; cs[t][1] = p[1]; cs[t][2] = p[2];
    }
    __syncthreads();
    if (t < Jj) {
        float x = cs[t][0], y = cs[t][1], z = cs[t][2];
        float d2[Jj];
        #pragma unroll
        for (int jj = 0; jj < Jj; ++jj) {
            float dx = x - cs[jj][0], dy = y - cs[jj][1], dz = z - cs[jj][2];
            d2[jj] = dx*dx + dy*dy + dz*dz;
        }
        unsigned int used = 0u;
        int out_base = (b * Jj + t) * KNN;
        #pragma unroll
        for (int r = 0; r <= KNN; ++r) {
            int best = -1; float bd = INFINITY;
            #pragma unroll
            for (int jj = 0; jj < Jj; ++jj)
                if (!((used >> jj) & 1u) && d2[jj] < bd) { bd = d2[jj]; best = jj; }
            used |= (1u << best);
            if (r > 0) nbr[out_base + r - 1] = best;
        }
    }
}

// ---------------------------------------------------------------------------
// fp32 -> bf16 elementwise (n4 = n/4)
__global__ __launch_bounds__(256)
void cvt_bf16_kernel(const float* __restrict__ in, unsigned short* __restrict__ out, int n4) {
    int i = blockIdx.x * 256 + threadIdx.x;
    if (i < n4) {
        float4 v = ((const float4*)in)[i];
        ushort4 o; o.x = f2bf(v.x); o.y = f2bf(v.y); o.z = f2bf(v.z); o.w = f2bf(v.w);
        ((ushort4*)out)[i] = o;
    }
}

// ---------------------------------------------------------------------------
// ONE kernel for all 12 weight transposes (fp32 [K][N] -> bf16 [N][K]) + stats
__global__ __launch_bounds__(256)
void prep_weights_kernel(const float* __restrict__ wq, const float* __restrict__ wk,
                         const float* __restrict__ wv, const float* __restrict__ wp,
                         const float* __restrict__ wsw, const float* __restrict__ wsk,
                         unsigned short* __restrict__ wqkvT,
                         unsigned short* __restrict__ fbt, float* __restrict__ stats) {
    int bid = blockIdx.x;
    if (bid == 0 && threadIdx.x < 2) stats[threadIdx.x] = 0.0f;

    const float* src; unsigned short* dst;
    int ldin, ldout, tilesX, tile;
    constexpr size_t CH = (size_t)Cc * HD;
    if (bid < 3072) {
        int op = bid >> 9; tile = bid & 511; tilesX = 64;
        ldin = HD; ldout = Cc;
        const float* s3[3] = {wq, wk, wv};
        src = s3[op % 3] + (size_t)(op / 3) * CH;
        dst = wqkvT + (size_t)(op % 3) * HD * Cc + (size_t)(op / 3) * QKVN * Cc;
    } else if (bid < 4096) {
        int op = (bid - 3072) >> 9; tile = (bid - 3072) & 511; tilesX = 8;
        ldin = Cc; ldout = KFUSE;
        src = wp + (size_t)op * HD * Cc;
        dst = fbt + (size_t)op * Cc * KFUSE;
    } else {
        int q = bid - 4096; int op = q >> 6; tile = q & 63; tilesX = 8;
        ldin = Cc; ldout = KFUSE;
        const float* s4[4] = {wsw, wsw + (size_t)Cc * Cc, wsk, wsk};
        src = s4[op];
        dst = fbt + (size_t)(op & 1) * Cc * KFUSE + HD + (size_t)(op >> 1) * Cc;
    }
    int bx = tile % tilesX, by = tile / tilesX;
    int n0 = bx * 32, k0 = by * 32;

    __shared__ float t[32][33];
    int r = threadIdx.x >> 3, c4 = (threadIdx.x & 7) * 4;
    float4 v = *(const float4*)&src[(size_t)(k0 + r) * ldin + n0 + c4];
    t[r][c4+0] = v.x; t[r][c4+1] = v.y; t[r][c4+2] = v.z; t[r][c4+3] = v.w;
    __syncthreads();
    ushort4 o;
    o.x = f2bf(t[c4+0][r]); o.y = f2bf(t[c4+1][r]);
    o.z = f2bf(t[c4+2][r]); o.w = f2bf(t[c4+3][r]);
    *(ushort4*)&dst[(size_t)(n0 + r) * ldout + k0 + c4] = o;
}

// ---------------------------------------------------------------------------
// G = per-head wq_h @ wk_h^T (fp32). BM=BN=64, BK=32, 4x4 microtile.
// grid (4,4,8): x=mtile, y=ntile, z=head
__global__ __launch_bounds__(256)
void g_gemm_kernel(const float* __restrict__ wq, const float* __restrict__ wk,
                   float* __restrict__ G) {
    constexpr int LDR = 68;
    __shared__ float As[32][LDR];
    __shared__ float Ws[32][LDR];
    int h = blockIdx.z;
    int m0 = blockIdx.x * 64, n0 = blockIdx.y * 64;
    int tid = threadIdx.x;
    int ty = tid >> 4, tx = tid & 15;
    float acc[4][4] = {};
    for (int kb = 0; kb < 256; kb += 32) {
        #pragma unroll
        for (int it = 0; it < 2; ++it) {
            int c = tid + it * 256;
            int row = c >> 3, col = (c & 7) * 4;
            float4 v = *(const float4*)&wq[(size_t)(m0 + row)*HD + h*256 + kb + col];
            float4 u = *(const float4*)&wk[(size_t)(n0 + row)*HD + h*256 + kb + col];
            As[col+0][row] = v.x; As[col+1][row] = v.y;
            As[col+2][row] = v.z; As[col+3][row] = v.w;
            Ws[col+0][row] = u.x; Ws[col+1][row] = u.y;
            Ws[col+2][row] = u.z; Ws[col+3][row] = u.w;
        }
        __syncthreads();
        #pragma unroll
        for (int kk = 0; kk < 32; ++kk) {
            float4 a = *(const float4*)&As[kk][ty*4];
            float4 b = *(const float4*)&Ws[kk][tx*4];
            float av[4] = {a.x, a.y, a.z, a.w};
            float bv[4] = {b.x, b.y, b.z, b.w};
            #pragma unroll
            for (int i = 0; i < 4; ++i)
                #pragma unroll
                for (int j = 0; j < 4; ++j)
                    acc[i][j] += av[i] * bv[j];
        }
        __syncthreads();
    }
    #pragma unroll
    for (int i = 0; i < 4; ++i) {
        float4 o = {acc[i][0], acc[i][1], acc[i][2], acc[i][3]};
        *(float4*)&G[(size_t)(m0 + ty*4 + i)*HD + h*256 + n0 + tx*4] = o;
    }
}

// ---------------------------------------------------------------------------
// Wvp2[e][h*3+c] = sum_d wv[e][h*256+d] * wp[h*256+d][c].  grid (8), 256 thr
__global__ __launch_bounds__(256)
void wvp_kernel(const float* __restrict__ wv, const float* __restrict__ wp,
                float* __restrict__ Wvp2) {
    int h = blockIdx.x;
    __shared__ float wpc[256][3];
    int t = threadIdx.x;
    const float* p = &wp[(size_t)(h*256 + t) * Cc];
    wpc[t][0] = p[0]; wpc[t][1] = p[1]; wpc[t][2] = p[2];
    __syncthreads();
    const float* vr = &wv[(size_t)t*HD + h*256];
    float a0=0, a1=0, a2=0;
    for (int d = 0; d < 256; ++d) {
        float v = vr[d];
        a0 += v*wpc[d][0]; a1 += v*wpc[d][1]; a2 += v*wpc[d][2];
    }
    float* o = &Wvp2[(size_t)t*24 + h*3];
    o[0]=a0; o[1]=a1; o[2]=a2;
}

// ---------------------------------------------------------------------------
// vproj[j][o] = sum_e h0[j][e] * Wvp2[e][o], o<24.  8 rows/block, 256 thr.
__global__ __launch_bounds__(256)
void vproj_kernel(const float* __restrict__ h0, const float* __restrict__ Wvp2,
                  float* __restrict__ vproj) {
    __shared__ float hr[8][256];
    __shared__ float wl[6144];
    int t = threadIdx.x;
    int j0 = blockIdx.x * 8;
    #pragma unroll
    for (int i = 0; i < 6; ++i)
        *(float4*)&wl[t*4 + i*1024] = *(const float4*)&Wvp2[t*4 + i*1024];
    {
        int r = t >> 5, c = (t & 31) * 8;
        const float* src = &h0[(size_t)(j0 + r)*Cc + c];
        *(float4*)&hr[r][c]   = *(const float4*)src;
        *(float4*)&hr[r][c+4] = *(const float4*)(src + 4);
    }
    __syncthreads();
    int r = t >> 5, o = t & 31;
    if (o < 24) {
        float a = 0.0f;
        for (int e = 0; e < 256; ++e) a += hr[r][e] * wl[e*24 + o];
        vproj[(size_t)(j0 + r)*24 + o] = a;
    }
}

// ---------------------------------------------------------------------------
// precise layer-0 coords
__global__ __launch_bounds__(64)
void precise_kernel(const float* __restrict__ T, const float* __restrict__ h0,
                    const int* __restrict__ nbr, const float* __restrict__ vproj,
                    const float* __restrict__ wsl, const float* __restrict__ wsk,
                    float* __restrict__ coords) {
    int i = blockIdx.x;
    int b = i / Jj;
    int l = threadIdx.x;
    __shared__ float Ts[8][260];
    __shared__ float nb[8][260];
    __shared__ float hi[256];
    #pragma unroll
    for (int u = 0; u < 8; ++u) {
        int idx = u*64 + l;
        float4 v = *(const float4*)&T[(size_t)i*HD + idx*4];
        int hh = idx >> 6, dd = (idx & 63) * 4;
        *(float4*)&Ts[hh][dd] = v;
    }
    *(float4*)&hi[l*4] = *(const float4*)&h0[(size_t)i*Cc + l*4];
    int kq = l >> 3, s = l & 7;
    int njs = nbr[i*KNN + kq];
    const float* nrow = &h0[(size_t)(b*Jj + njs)*Cc];
    #pragma unroll
    for (int u = 0; u < 8; ++u)
        *(float4*)&nb[kq][(s*8+u)*4] = *(const float4*)&nrow[(s*8+u)*4];
    __syncthreads();

    int k = l >> 3, h = l & 7;
    float sacc = 0;
    #pragma unroll 8
    for (int d = 0; d < 256; d += 4) {
        float4 tv = *(const float4*)&Ts[h][d];
        float4 nv = *(const float4*)&nb[k][d];
        sacc += tv.x*nv.x + tv.y*nv.y + tv.z*nv.z + tv.w*nv.w;
    }
    float sc = sacc * 0.0625f;
    sc = (sc >= 0.0f) ? sc : 0.2f * sc;
    float m = sc;
    m = fmaxf(m, __shfl_xor(m, 8));
    m = fmaxf(m, __shfl_xor(m, 16));
    m = fmaxf(m, __shfl_xor(m, 32));
    float e = expf(sc - m);
    float den = e;
    den += __shfl_xor(den, 8); den += __shfl_xor(den, 16); den += __shfl_xor(den, 32);
    float w = e / den;

    int njk = nbr[i*KNN + k];
    const float* vp = &vproj[(size_t)(b*Jj + njk)*24 + h*3];
    float t0 = w * vp[0], t1 = w * vp[1], t2 = w * vp[2];
    #pragma unroll
    for (int u = 0; u < 4; ++u) {
        int e4 = l*4 + u;
        float hv = hi[e4];
        const float* w1 = &wsl[(size_t)e4*Cc];
        const float* w2 = &wsk[(size_t)e4*Cc];
        t0 += hv * (w1[0] + w2[0]);
        t1 += hv * (w1[1] + w2[1]);
        t2 += hv * (w1[2] + w2[2]);
    }
    #pragma unroll
    for (int sft = 1; sft < 64; sft <<= 1) {
        t0 += __shfl_xor(t0, sft); t1 += __shfl_xor(t1, sft); t2 += __shfl_xor(t2, sft);
    }
    if (l == 0) {
        coords[i*3+0] = fmaxf(t0, 0.0f);
        coords[i*3+1] = fmaxf(t1, 0.0f);
        coords[i*3+2] = fmaxf(t2, 0.0f);
    }
}

// ---------------------------------------------------------------------------
// fp32 GEMM 128x128, BK=16, 256 thr, split 4+4 microtile, dbuf LDS.
// A[Mx256] @ W[256x2048] -> C. All LDS access stride<=4 floats (2-way max).
__global__ __launch_bounds__(256)
void sgemm128_kernel(const float* __restrict__ A, const float* __restrict__ W,
                     float* __restrict__ C) {
    constexpr int LDR = 132;
    __shared__ float As[2][16][LDR];
    __shared__ float Ws[2][16][LDR];
    int tid = threadIdx.x;
    int bm = blockIdx.x * 128, bn = blockIdx.y * 128;
    int ty = tid >> 4, tx = tid & 15;
    int c1 = tid + 256;
    int ar0 = tid >> 2, ak0 = (tid & 3) * 4;
    int ar1 = c1 >> 2,  ak1 = (c1 & 3) * 4;
    int wr0 = tid >> 5, wn0 = (tid & 31) * 4;
    int wr1 = c1 >> 5,  wn1 = (c1 & 31) * 4;

    float4 ra0, ra1, rw0, rw1;
    float acc[8][8] = {};

#define LOADG(k0)                                                             \
    ra0 = *(const float4*)&A[(size_t)(bm + ar0)*Cc + (k0) + ak0];             \
    ra1 = *(const float4*)&A[(size_t)(bm + ar1)*Cc + (k0) + ak1];             \
    rw0 = *(const float4*)&W[(size_t)((k0) + wr0)*HD + bn + wn0];             \
    rw1 = *(const float4*)&W[(size_t)((k0) + wr1)*HD + bn + wn1];

#define STORE(bf)                                                             \
    As[bf][ak0+0][ar0] = ra0.x; As[bf][ak0+1][ar0] = ra0.y;                   \
    As[bf][ak0+2][ar0] = ra0.z; As[bf][ak0+3][ar0] = ra0.w;                   \
    As[bf][ak1+0][ar1] = ra1.x; As[bf][ak1+1][ar1] = ra1.y;                   \
    As[bf][ak1+2][ar1] = ra1.z; As[bf][ak1+3][ar1] = ra1.w;                   \
    *(float4*)&Ws[bf][wr0][wn0] = rw0;                                        \
    *(float4*)&Ws[bf][wr1][wn1] = rw1;

#define COMPUTE(bf)                                                           \
    _Pragma("unroll")                                                         \
    for (int kk = 0; kk < 16; ++kk) {                                         \
        float4 a0 = *(const float4*)&As[bf][kk][ty*4];                        \
        float4 a1 = *(const float4*)&As[bf][kk][64 + ty*4];                   \
        float4 b0 = *(const float4*)&Ws[bf][kk][tx*4];                        \
        float4 b1 = *(const float4*)&Ws[bf][kk][64 + tx*4];                   \
        float av[8] = {a0.x,a0.y,a0.z,a0.w,a1.x,a1.y,a1.z,a1.w};              \
        float bv[8] = {b0.x,b0.y,b0.z,b0.w,b1.x,b1.y,b1.z,b1.w};              \
        _Pragma("unroll")                                                     \
        for (int i = 0; i < 8; ++i)                                           \
            _Pragma("unroll")                                                 \
            for (int j = 0; j < 8; ++j)                                       \
                acc[i][j] += av[i] * bv[j];                                   \
    }

    LOADG(0)
    STORE(0)
    int buf = 0;
    for (int k0 = 16; k0 < 256; k0 += 16) {
        __syncthreads();
        LOADG(k0)
        COMPUTE(buf)
        STORE(buf ^ 1)
        buf ^= 1;
    }
    __syncthreads();
    COMPUTE(buf)
#undef LOADG
#undef STORE
#undef COMPUTE

    #pragma unroll
    for (int i = 0; i < 4; ++i) {
        float* p0 = C + (size_t)(bm + ty*4 + i)*HD + bn;
        float4 o00 = {acc[i][0], acc[i][1], acc[i][2], acc[i][3]};
        float4 o01 = {acc[i][4], acc[i][5], acc[i][6], acc[i][7]};
        *(float4*)(p0 + tx*4)      = o00;
        *(float4*)(p0 + 64 + tx*4) = o01;
        float* p1 = C + (size_t)(bm + 64 + ty*4 + i)*HD + bn;
        float4 o10 = {acc[4+i][0], acc[4+i][1], acc[4+i][2], acc[4+i][3]};
        float4 o11 = {acc[4+i][4], acc[4+i][5], acc[4+i][6], acc[4+i][7]};
        *(float4*)(p1 + tx*4)      = o10;
        *(float4*)(p1 + 64 + tx*4) = o11;
    }
}

// ---------------------------------------------------------------------------
// bf16 MFMA GEMM, B^T input ([N][K]), segmented A along K, fp32 accum.
// 256 threads = 4 waves in 2x2; per-wave tile (BM/2)x(BN/2).
template<int BM, int BN, int BK, int NSEG, bool RELU_STATS, bool OUT_BF16>
__global__ __launch_bounds__(256)
void gemm_bt_kernel(const unsigned short* __restrict__ A0, int lda0, int klen0,
                    const unsigned short* __restrict__ A1, int lda1, int klen1,
                    const unsigned short* __restrict__ A2, int lda2, int klen2,
                    const unsigned short* __restrict__ Bt, int ldb,
                    void* __restrict__ Cv, int ldc, float* __restrict__ stat) {
    constexpr int WM = BM/2, WN = BN/2;
    constexpr int MW = WM/16, NW = WN/16, KW = BK/32;
    constexpr int CHUNKA = BM*BK/8;
    constexpr int CHUNKB = BN*BK/8;
    constexpr int KB8 = BK/8;
    __shared__ unsigned short As[BM*BK];
    __shared__ unsigned short Bs[BN*BK];
    __shared__ float red[4];

    int tid = threadIdx.x;
    int wid = tid >> 6, lane = tid & 63;
    int wr = wid >> 1, wc = wid & 1;
    int bm = blockIdx.x * BM, bn = blockIdx.y * BN;

    f32x4 acc[MW][NW];
    #pragma unroll
    for (int m = 0; m < MW; ++m)
        #pragma unroll
        for (int n = 0; n < NW; ++n)
            acc[m][n] = (f32x4){0.f, 0.f, 0.f, 0.f};

    const unsigned short* Aseg[3] = {A0, A1, A2};
    const int ldas[3] = {lda0, lda1, lda2};
    const int klens[3] = {klen0, klen1, klen2};

    int kglob = 0;
    for (int seg = 0; seg < NSEG; ++seg) {
        const unsigned short* A = Aseg[seg];
        const int lda = ldas[seg];
        const int klen = klens[seg];
        for (int k0 = 0; k0 < klen; k0 += BK) {
            #pragma unroll
            for (int it = 0; it < CHUNKA/256; ++it) {
                int c = tid + it*256;
                int row = c / KB8, kp = c % KB8;
                __builtin_amdgcn_global_load_lds(
                    (const __attribute__((address_space(1))) unsigned int*)
                        (A + (size_t)(bm + row)*lda + k0 + kp*8),
                    (__attribute__((address_space(3))) unsigned int*)(As + c*8),
                    16, 0, 0);
            }
            #pragma unroll
            for (int it = 0; it < CHUNKB/256; ++it) {
                int c = tid + it*256;
                int row = c / KB8, kp = c % KB8;
                __builtin_amdgcn_global_load_lds(
                    (const __attribute__((address_space(1))) unsigned int*)
                        (Bt + (size_t)(bn + row)*ldb + kglob + k0 + kp*8),
                    (__attribute__((address_space(3))) unsigned int*)(Bs + c*8),
                    16, 0, 0);
            }
            __syncthreads();
            #pragma unroll
            for (int kp = 0; kp < KW; ++kp) {
                short8 af[MW], bf[NW];
                #pragma unroll
                for (int m = 0; m < MW; ++m)
                    af[m] = *(const short8*)&As[(wr*WM + m*16 + (lane & 15))*BK
                                               + kp*32 + (lane >> 4)*8];
                #pragma unroll
                for (int n = 0; n < NW; ++n)
                    bf[n] = *(const short8*)&Bs[(wc*WN + n*16 + (lane & 15))*BK
                                               + kp*32 + (lane >> 4)*8];
                #pragma unroll
                for (int m = 0; m < MW; ++m)
                    #pragma unroll
                    for (int n = 0; n < NW; ++n)
                        acc[m][n] = __builtin_amdgcn_mfma_f32_16x16x32_bf16(
                            af[m], bf[n], acc[m][n], 0, 0, 0);
            }
            __syncthreads();
        }
        kglob += klen;
    }

    int cr = (lane >> 4)*4, cc = lane & 15;
    float bsum = 0.0f;
    #pragma unroll
    for (int m = 0; m < MW; ++m)
        #pragma unroll
        for (int n = 0; n < NW; ++n)
            #pragma unroll
            for (int j = 0; j < 4; ++j) {
                float v = acc[m][n][j];
                if (RELU_STATS) { v = fmaxf(v, 0.0f); bsum += v; }
                size_t row = bm + wr*WM + m*16 + cr + j;
                size_t col = bn + wc*WN + n*16 + cc;
                if (OUT_BF16) ((unsigned short*)Cv)[row*ldc + col] = f2bf(v);
                else          ((float*)Cv)[row*ldc + col] = v;
            }
    if (RELU_STATS) {
        #pragma unroll
        for (int sft = 1; sft < 64; sft <<= 1) bsum += __shfl_xor(bsum, sft);
        if (lane == 0) red[wid] = bsum;
        __syncthreads();
        if (tid == 0) atomicAdd(stat, red[0] + red[1] + red[2] + red[3]);
    }
}

// ---------------------------------------------------------------------------
// attention v2: one wave per (batch, head). Scores for all 21 rows x 8 nbrs
// from cache-resident QKV; V pass coalesced; softmax weights via tiny LDS.
__global__ __launch_bounds__(64)
void attn2_kernel(const unsigned short* __restrict__ QKV,
                  const int* __restrict__ nbr, unsigned short* __restrict__ att) {
    int bh = blockIdx.x;
    int b = bh >> 3, h = bh & 7;
    int lane = threadIdx.x;
    __shared__ int nbs[Jj][KNN];
    __shared__ float wsm[Jj][KNN];
    for (int c = lane; c < Jj*KNN; c += 64)
        nbs[c >> 3][c & 7] = nbr[(b*Jj + (c >> 3))*KNN + (c & 7)];
    __syncthreads();

    const unsigned short* base = QKV + (size_t)b*Jj*QKVN;
    int k = lane >> 3, sub = lane & 7;
    for (int r = 0; r < Jj; ++r) {
        int n = nbs[r][k];
        const unsigned short* qrow = base + (size_t)r*QKVN + h*Dd + sub*32;
        const unsigned short* krow = base + (size_t)n*QKVN + HD + h*Dd + sub*32;
        float p = 0.0f;
        #pragma unroll
        for (int i = 0; i < 4; ++i) {
            u16x8 qv = *(const u16x8*)(qrow + i*8);
            u16x8 kv = *(const u16x8*)(krow + i*8);
            #pragma unroll
            for (int j = 0; j < 8; ++j) p += bf2f(qv[j]) * bf2f(kv[j]);
        }
        p += __shfl_xor(p, 1); p += __shfl_xor(p, 2); p += __shfl_xor(p, 4);
        float s = p * 0.0625f;
        s = (s >= 0.0f) ? s : 0.2f * s;
        float m = s;
        m = fmaxf(m, __shfl_xor(m, 8));
        m = fmaxf(m, __shfl_xor(m, 16));
        m = fmaxf(m, __shfl_xor(m, 32));
        float e = expf(s - m);
        float den = e;
        den += __shfl_xor(den, 8); den += __shfl_xor(den, 16); den += __shfl_xor(den, 32);
        if (sub == 0) wsm[r][k] = e / den;
    }
    __syncthreads();

    int d4 = lane * 4;
    for (int r = 0; r < Jj; ++r) {
        float o0=0, o1=0, o2=0, o3=0;
        #pragma unroll
        for (int k2 = 0; k2 < KNN; ++k2) {
            float w = wsm[r][k2];
            ushort4 vv = *(const ushort4*)(base + (size_t)nbs[r][k2]*QKVN
                                           + 2*HD + h*Dd + d4);
            o0 += w*bf2f(vv.x); o1 += w*bf2f(vv.y);
            o2 += w*bf2f(vv.z); o3 += w*bf2f(vv.w);
        }
        ushort4 ou; ou.x=f2bf(o0); ou.y=f2bf(o1); ou.z=f2bf(o2); ou.w=f2bf(o3);
        *(ushort4*)&att[(size_t)(b*Jj + r)*HD + h*Dd + d4] = ou;
    }
}

// ---------------------------------------------------------------------------
__global__ __launch_bounds__(64)
void final_kernel(const float* __restrict__ h, const float* __restrict__ fcw,
                  const float* __restrict__ fcb, const float* __restrict__ stats,
                  float* __restrict__ out) {
    int row = blockIdx.x, lane = threadIdx.x;
    const float4 hv = *(const float4*)(h + (size_t)row*Cc + lane*4);
    float a0=0, a1=0, a2=0;
    const float hx[4] = {hv.x, hv.y, hv.z, hv.w};
    #pragma unroll
    for (int i = 0; i < 4; ++i) {
        int c = lane*4 + i;
        a0 += hx[i]*fcw[c*3+0]; a1 += hx[i]*fcw[c*3+1]; a2 += hx[i]*fcw[c*3+2];
    }
    #pragma unroll
    for (int s = 32; s > 0; s >>= 1) {
        a0 += __shfl_xor(a0, s); a1 += __shfl_xor(a1, s); a2 += __shfl_xor(a2, s);
    }
    if (lane == 0) {
        out[row*3+0] = a0 + fcb[0];
        out[row*3+1] = a1 + fcb[1];
        out[row*3+2] = a2 + fcb[2];
        if (row == 0)
            out[(size_t)Mrows*3] =
                (stats[0] + stats[1]) * (0.5f / ((float)Mrows * (float)Cc));
    }
}

// ---------------------------------------------------------------------------
extern "C" void kernel_launch(void* const* d_in, const int* in_sizes, int n_in,
                              void* d_out, int out_size, void* d_ws, size_t ws_size,
                              hipStream_t stream) {
    (void)in_sizes; (void)n_in; (void)out_size; (void)ws_size;
    const float* jf     = (const float*)d_in[0];
    const float* wq     = (const float*)d_in[1];
    const float* wk     = (const float*)d_in[2];
    const float* wv     = (const float*)d_in[3];
    const float* wp     = (const float*)d_in[4];
    const float* wsw    = (const float*)d_in[5];
    const float* wskip0 = (const float*)d_in[6];
    const float* fcw    = (const float*)d_in[7];
    const float* fcb    = (const float*)d_in[8];
    float* out = (float*)d_out;

    char* wsb = (char*)d_ws;
    unsigned short* QKVb  = (unsigned short*)(wsb + OFF_QKV);
    unsigned short* attb  = (unsigned short*)(wsb + OFF_ATT);
    float*          Tm    = (float*)(wsb + OFF_T);
    float*          G     = (float*)(wsb + OFF_G);
    unsigned short* jfb   = (unsigned short*)(wsb + OFF_JFB);
    unsigned short* h1b   = (unsigned short*)(wsb + OFF_H1B);
    float*          h2f   = (float*)(wsb + OFF_H2F);
    unsigned short* wqkvT = (unsigned short*)(wsb + OFF_WQKVT);
    unsigned short* fbt   = (unsigned short*)(wsb + OFF_FBT);
    float*          Wvp   = (float*)(wsb + OFF_WVP);
    float*          vproj = (float*)(wsb + OFF_VPROJ);
    float*          crd   = (float*)(wsb + OFF_CRD);
    int*            nbr0  = (int*)(wsb + OFF_NBR0);
    int*            nbr1  = (int*)(wsb + OFF_NBR1);
    float*          stats = (float*)(wsb + OFF_STAT);

    // ---- prep ----
    prep_weights_kernel<<<4352, 256, 0, stream>>>(wq, wk, wv, wp, wsw, wskip0,
                                                  wqkvT, fbt, stats);
    cvt_bf16_kernel<<<(Mrows*Cc/4 + 255)/256, 256, 0, stream>>>(jf, jfb, Mrows*Cc/4);
    g_gemm_kernel<<<dim3(4, 4, 8), 256, 0, stream>>>(wq, wk, G);
    sgemm128_kernel<<<dim3(Mrows/128, HD/128), 256, 0, stream>>>(jf, G, Tm);
    wvp_kernel<<<8, 256, 0, stream>>>(wv, wp, Wvp);
    vproj_kernel<<<Mrows/8, 256, 0, stream>>>(jf, Wvp, vproj);

    // ---- layer 0 ----
    knn_kernel<<<Bb, 64, 0, stream>>>(jf, Cc, nbr0);
    precise_kernel<<<Mrows, 64, 0, stream>>>(Tm, jf, nbr0, vproj, wsw, wskip0, crd);
    gemm_bt_kernel<128,128,64,1,false,true><<<dim3(Mrows/128, QKVN/128), 256, 0, stream>>>(
        jfb, Cc, Cc, jfb, Cc, 0, jfb, Cc, 0, wqkvT, Cc, QKVb, QKVN, nullptr);
    attn2_kernel<<<Bb*Hh, 64, 0, stream>>>(QKVb, nbr0, attb);
    gemm_bt_kernel<64,128,64,3,true,true><<<dim3(Mrows/64, Cc/128), 256, 0, stream>>>(
        attb, HD, HD, jfb, Cc, Cc, jfb, Cc, Cc, fbt, KFUSE, h1b, Cc, &stats[0]);

    // ---- layer 1 ----
    knn_kernel<<<Bb, 64, 0, stream>>>(crd, 3, nbr1);
    gemm_bt_kernel<128,128,64,1,false,true><<<dim3(Mrows/128, QKVN/128), 256, 0, stream>>>(
        h1b, Cc, Cc, h1b, Cc, 0, h1b, Cc, 0, wqkvT + (size_t)QKVN*Cc, Cc, QKVb, QKVN, nullptr);
    attn2_kernel<<<Bb*Hh, 64, 0, stream>>>(QKVb, nbr1, attb);
    gemm_bt_kernel<64,128,64,3,true,false><<<dim3(Mrows/64, Cc/128), 256, 0, stream>>>(
        attb, HD, HD, h1b, Cc, Cc, jfb, Cc, Cc, fbt + (size_t)Cc*KFUSE, KFUSE, h2f, Cc, &stats[1]);

    // ---- final ----
    final_kernel<<<Mrows, 64, 0, stream>>>(h2f, fcw, fcb, stats, out);
}

// Round 5
// 445.396 us; speedup vs baseline: 1.0107x; 1.0107x over previous
//
#include <hip/hip_runtime.h>
#include <hip/hip_bf16.h>
#include <math.h>

namespace {
constexpr int Bb = 256, Jj = 21, Cc = 256, Hh = 8, Dd = 256;
constexpr int Mrows = Bb * Jj;      // 5376
constexpr int HD    = Hh * Dd;      // 2048
constexpr int QKVN  = 3 * HD;       // 6144
constexpr int KNN   = 8;
constexpr int KFUSE = HD + Cc + Cc; // 2560

// ---- workspace byte offsets ----
constexpr size_t OFF_QKV   = 0;                                   // bf16 5376x6144
constexpr size_t OFF_ATT   = OFF_QKV   + (size_t)Mrows*QKVN*2;    // bf16 5376x2048
constexpr size_t OFF_G     = OFF_ATT   + (size_t)Mrows*HD*2;      // f32  8x256x256
constexpr size_t OFF_JFB   = OFF_G     + (size_t)Hh*Cc*Cc*4;      // bf16 5376x256
constexpr size_t OFF_H1B   = OFF_JFB   + (size_t)Mrows*Cc*2;      // bf16 5376x256
constexpr size_t OFF_H2F   = OFF_H1B   + (size_t)Mrows*Cc*2;      // f32  5376x256
constexpr size_t OFF_WQKVT = OFF_H2F   + (size_t)Mrows*Cc*4;      // bf16 2x6144x256
constexpr size_t OFF_FBT   = OFF_WQKVT + (size_t)2*QKVN*Cc*2;     // bf16 2x256x2560
constexpr size_t OFF_WVP   = OFF_FBT   + (size_t)2*Cc*KFUSE*2;    // f32  256x24
constexpr size_t OFF_VPROJ = OFF_WVP   + (size_t)Cc*24*4;         // f32  5376x24
constexpr size_t OFF_P     = OFF_VPROJ + (size_t)Mrows*24*4;      // f32  5376x32
constexpr size_t OFF_WSUM  = OFF_P     + (size_t)Mrows*32*4;      // f32  256x4
constexpr size_t OFF_CRD   = OFF_WSUM  + (size_t)Cc*4*4;          // f32  5376x4
constexpr size_t OFF_NBR0  = OFF_CRD   + (size_t)Mrows*4*4;       // int  5376x8
constexpr size_t OFF_NBR1  = OFF_NBR0  + (size_t)Mrows*KNN*4;
constexpr size_t OFF_STAT  = OFF_NBR1  + (size_t)Mrows*KNN*4;     // 2 f32
} // namespace

typedef short short8 __attribute__((ext_vector_type(8)));
typedef unsigned short u16x8 __attribute__((ext_vector_type(8)));
typedef float f32x4 __attribute__((ext_vector_type(4)));

__device__ __forceinline__ unsigned short f2bf(float x) {
    unsigned int u = __float_as_uint(x);
    u = u + 0x7fffu + ((u >> 16) & 1u);            // round-to-nearest-even
    return (unsigned short)(u >> 16);
}
__device__ __forceinline__ float bf2f(unsigned short b) {
    return __uint_as_float(((unsigned int)b) << 16);
}

// ---------------------------------------------------------------------------
// exact stable-argsort kNN: ranks 1..8 by (d2, index) ascending
__global__ __launch_bounds__(64)
void knn_kernel(const float* __restrict__ src, int ld, int* __restrict__ nbr) {
    int b = blockIdx.x;
    __shared__ float cs[Jj][3];
    int t = threadIdx.x;
    if (t < Jj) {
        const float* p = src + (size_t)(b * Jj + t) * ld;
        cs[t][0] = p[0]; cs[t][1] = p[1]; cs[t][2] = p[2];
    }
    __syncthreads();
    if (t < Jj) {
        float x = cs[t][0], y = cs[t][1], z = cs[t][2];
        float d2[Jj];
        #pragma unroll
        for (int jj = 0; jj < Jj; ++jj) {
            float dx = x - cs[jj][0], dy = y - cs[jj][1], dz = z - cs[jj][2];
            d2[jj] = dx*dx + dy*dy + dz*dz;
        }
        unsigned int used = 0u;
        int out_base = (b * Jj + t) * KNN;
        #pragma unroll
        for (int r = 0; r <= KNN; ++r) {
            int best = -1; float bd = INFINITY;
            #pragma unroll
            for (int jj = 0; jj < Jj; ++jj)
                if (!((used >> jj) & 1u) && d2[jj] < bd) { bd = d2[jj]; best = jj; }
            used |= (1u << best);
            if (r > 0) nbr[out_base + r - 1] = best;
        }
    }
}

// ---------------------------------------------------------------------------
// fp32 -> bf16 elementwise (n4 = n/4)
__global__ __launch_bounds__(256)
void cvt_bf16_kernel(const float* __restrict__ in, unsigned short* __restrict__ out, int n4) {
    int i = blockIdx.x * 256 + threadIdx.x;
    if (i < n4) {
        float4 v = ((const float4*)in)[i];
        ushort4 o; o.x = f2bf(v.x); o.y = f2bf(v.y); o.z = f2bf(v.z); o.w = f2bf(v.w);
        ((ushort4*)out)[i] = o;
    }
}

// ---------------------------------------------------------------------------
// All 12 weight transposes (fp32 [K][N] -> bf16 [N][K]) + stats zero + wsum.
__global__ __launch_bounds__(256)
void prep_weights_kernel(const float* __restrict__ wq, const float* __restrict__ wk,
                         const float* __restrict__ wv, const float* __restrict__ wp,
                         const float* __restrict__ wsw, const float* __restrict__ wsk,
                         unsigned short* __restrict__ wqkvT,
                         unsigned short* __restrict__ fbt, float* __restrict__ stats,
                         float* __restrict__ wsum) {
    int bid = blockIdx.x;
    if (bid == 4352) {       // wsum[e][c] = ws0[e][c] + wskip0[e][c], c<3
        int e = threadIdx.x;
        float4 o;
        o.x = wsw[(size_t)e*Dd + 0] + wsk[(size_t)e*Dd + 0];
        o.y = wsw[(size_t)e*Dd + 1] + wsk[(size_t)e*Dd + 1];
        o.z = wsw[(size_t)e*Dd + 2] + wsk[(size_t)e*Dd + 2];
        o.w = 0.0f;
        *(float4*)&wsum[e*4] = o;
        if (bid == 4352 && e < 2) stats[e] = 0.0f;
        return;
    }
    const float* src; unsigned short* dst;
    int ldin, ldout, tilesX, tile;
    constexpr size_t CH = (size_t)Cc * HD;
    if (bid < 3072) {
        int op = bid >> 9; tile = bid & 511; tilesX = 64;
        ldin = HD; ldout = Cc;
        const float* s3[3] = {wq, wk, wv};
        src = s3[op % 3] + (size_t)(op / 3) * CH;
        dst = wqkvT + (size_t)(op % 3) * HD * Cc + (size_t)(op / 3) * QKVN * Cc;
    } else if (bid < 4096) {
        int op = (bid - 3072) >> 9; tile = (bid - 3072) & 511; tilesX = 8;
        ldin = Cc; ldout = KFUSE;
        src = wp + (size_t)op * HD * Cc;
        dst = fbt + (size_t)op * Cc * KFUSE;
    } else {
        int q = bid - 4096; int op = q >> 6; tile = q & 63; tilesX = 8;
        ldin = Cc; ldout = KFUSE;
        const float* s4[4] = {wsw, wsw + (size_t)Cc * Cc, wsk, wsk};
        src = s4[op];
        dst = fbt + (size_t)(op & 1) * Cc * KFUSE + HD + (size_t)(op >> 1) * Cc;
    }
    int bx = tile % tilesX, by = tile / tilesX;
    int n0 = bx * 32, k0 = by * 32;

    __shared__ float t[32][33];
    int r = threadIdx.x >> 3, c4 = (threadIdx.x & 7) * 4;
    float4 v = *(const float4*)&src[(size_t)(k0 + r) * ldin + n0 + c4];
    t[r][c4+0] = v.x; t[r][c4+1] = v.y; t[r][c4+2] = v.z; t[r][c4+3] = v.w;
    __syncthreads();
    ushort4 o;
    o.x = f2bf(t[c4+0][r]); o.y = f2bf(t[c4+1][r]);
    o.z = f2bf(t[c4+2][r]); o.w = f2bf(t[c4+3][r]);
    *(ushort4*)&dst[(size_t)(n0 + r) * ldout + k0 + c4] = o;
}

// ---------------------------------------------------------------------------
// G[h][c][c'] = sum_d wq[c][h*256+d] * wk[c'][h*256+d] (fp32, exact path)
// BM=BN=64, BK=32, 4x4 microtile. grid (4,4,8)
__global__ __launch_bounds__(256)
void g_gemm_kernel(const float* __restrict__ wq, const float* __restrict__ wk,
                   float* __restrict__ G) {
    constexpr int LDR = 68;
    __shared__ float As[32][LDR];
    __shared__ float Ws[32][LDR];
    int h = blockIdx.z;
    int m0 = blockIdx.x * 64, n0 = blockIdx.y * 64;
    int tid = threadIdx.x;
    int ty = tid >> 4, tx = tid & 15;
    float acc[4][4] = {};
    for (int kb = 0; kb < 256; kb += 32) {
        #pragma unroll
        for (int it = 0; it < 2; ++it) {
            int c = tid + it * 256;
            int row = c >> 3, col = (c & 7) * 4;
            float4 v = *(const float4*)&wq[(size_t)(m0 + row)*HD + h*256 + kb + col];
            float4 u = *(const float4*)&wk[(size_t)(n0 + row)*HD + h*256 + kb + col];
            As[col+0][row] = v.x; As[col+1][row] = v.y;
            As[col+2][row] = v.z; As[col+3][row] = v.w;
            Ws[col+0][row] = u.x; Ws[col+1][row] = u.y;
            Ws[col+2][row] = u.z; Ws[col+3][row] = u.w;
        }
        __syncthreads();
        #pragma unroll
        for (int kk = 0; kk < 32; ++kk) {
            float4 a = *(const float4*)&As[kk][ty*4];
            float4 b = *(const float4*)&Ws[kk][tx*4];
            float av[4] = {a.x, a.y, a.z, a.w};
            float bv[4] = {b.x, b.y, b.z, b.w};
            #pragma unroll
            for (int i = 0; i < 4; ++i)
                #pragma unroll
                for (int j = 0; j < 4; ++j)
                    acc[i][j] += av[i] * bv[j];
        }
        __syncthreads();
    }
    #pragma unroll
    for (int i = 0; i < 4; ++i) {
        float4 o = {acc[i][0], acc[i][1], acc[i][2], acc[i][3]};
        *(float4*)&G[(size_t)h*Cc*Cc + (size_t)(m0 + ty*4 + i)*Cc + n0 + tx*4] = o;
    }
}

// ---------------------------------------------------------------------------
// Wvp2[e][h*3+c] = sum_d wv[e][h*256+d] * wp[h*256+d][c].  grid (8), 256 thr
__global__ __launch_bounds__(256)
void wvp_kernel(const float* __restrict__ wv, const float* __restrict__ wp,
                float* __restrict__ Wvp2) {
    int h = blockIdx.x;
    __shared__ float wpc[256][3];
    int t = threadIdx.x;
    const float* p = &wp[(size_t)(h*256 + t) * Cc];
    wpc[t][0] = p[0]; wpc[t][1] = p[1]; wpc[t][2] = p[2];
    __syncthreads();
    const float* vr = &wv[(size_t)t*HD + h*256];
    float a0=0, a1=0, a2=0;
    for (int d = 0; d < 256; ++d) {
        float v = vr[d];
        a0 += v*wpc[d][0]; a1 += v*wpc[d][1]; a2 += v*wpc[d][2];
    }
    float* o = &Wvp2[(size_t)t*24 + h*3];
    o[0]=a0; o[1]=a1; o[2]=a2;
}

// ---------------------------------------------------------------------------
// vproj[j][o] = sum_e h0[j][e] * Wvp2[e][o], o<24.  8 rows/block, 256 thr.
__global__ __launch_bounds__(256)
void vproj_kernel(const float* __restrict__ h0, const float* __restrict__ Wvp2,
                  float* __restrict__ vproj) {
    __shared__ float hr[8][256];
    __shared__ float wl[6144];
    int t = threadIdx.x;
    int j0 = blockIdx.x * 8;
    #pragma unroll
    for (int i = 0; i < 6; ++i)
        *(float4*)&wl[t*4 + i*1024] = *(const float4*)&Wvp2[t*4 + i*1024];
    {
        int r = t >> 5, c = (t & 31) * 8;
        const float* src = &h0[(size_t)(j0 + r)*Cc + c];
        *(float4*)&hr[r][c]   = *(const float4*)src;
        *(float4*)&hr[r][c+4] = *(const float4*)(src + 4);
    }
    __syncthreads();
    int r = t >> 5, o = t & 31;
    if (o < 24) {
        float a = 0.0f;
        for (int e = 0; e < 256; ++e) a += hr[r][e] * wl[e*24 + o];
        vproj[(size_t)(j0 + r)*24 + o] = a;
    }
}

// ---------------------------------------------------------------------------
// Fused per-(batch,head) score path (fp32-exact, replaces T GEMM + heavy dot):
// wave w owns rows i0=6w..; lane owns c' = lane*4..+3. U[i][c'] in registers.
// Then scores over 8 nbrs (wave shfl reduce), leaky+softmax, P += w*vproj.
__global__ __launch_bounds__(256)
void score_kernel(const float* __restrict__ h0, const float* __restrict__ G,
                  const int* __restrict__ nbr, const float* __restrict__ vproj,
                  float* __restrict__ P) {
    int bh = blockIdx.x;
    int b = bh >> 3, h = bh & 7;
    int tid = threadIdx.x, lane = tid & 63, w = tid >> 6;
    __shared__ int nbs[Jj][KNN];
    for (int c = tid; c < Jj*KNN; c += 256)
        nbs[c >> 3][c & 7] = nbr[(b*Jj + (c >> 3))*KNN + (c & 7)];

    const float* hb = h0 + (size_t)b*Jj*Cc;
    const float* Gh = G + (size_t)h*Cc*Cc + lane*4;
    int i0 = w * 6;
    int ni = (w == 3) ? 3 : 6;

    f32x4 U[6];
    #pragma unroll
    for (int i = 0; i < 6; ++i) U[i] = (f32x4){0.f,0.f,0.f,0.f};

    for (int c = 0; c < Cc; c += 4) {
        f32x4 g0 = *(const f32x4*)(Gh + (size_t)(c+0)*Cc);
        f32x4 g1 = *(const f32x4*)(Gh + (size_t)(c+1)*Cc);
        f32x4 g2 = *(const f32x4*)(Gh + (size_t)(c+2)*Cc);
        f32x4 g3 = *(const f32x4*)(Gh + (size_t)(c+3)*Cc);
        #pragma unroll
        for (int i = 0; i < 6; ++i) {
            int ii = i0 + i; if (ii >= Jj) ii = Jj - 1;   // uniform clamp
            f32x4 hv = *(const f32x4*)(hb + (size_t)ii*Cc + c);  // wave-uniform
            U[i] += hv[0]*g0 + hv[1]*g1 + hv[2]*g2 + hv[3]*g3;
        }
    }
    __syncthreads();

    for (int i = 0; i < 6; ++i) {
        if (i >= ni) break;
        int ri = i0 + i;
        float sc[KNN];
        #pragma unroll
        for (int k = 0; k < KNN; ++k) {
            int n = nbs[ri][k];
            f32x4 hv = *(const f32x4*)(hb + (size_t)n*Cc + lane*4);
            float p = U[i][0]*hv[0] + U[i][1]*hv[1] + U[i][2]*hv[2] + U[i][3]*hv[3];
            #pragma unroll
            for (int s = 1; s < 64; s <<= 1) p += __shfl_xor(p, s);
            sc[k] = p * 0.0625f;
        }
        float mx = -INFINITY;
        #pragma unroll
        for (int k = 0; k < KNN; ++k) {
            float s = sc[k];
            s = (s >= 0.0f) ? s : 0.2f * s;
            sc[k] = s; mx = fmaxf(mx, s);
        }
        float den = 0.0f;
        #pragma unroll
        for (int k = 0; k < KNN; ++k) { sc[k] = expf(sc[k] - mx); den += sc[k]; }
        float inv = 1.0f / den;
        if (lane < 3) {
            float a = 0.0f;
            #pragma unroll
            for (int k = 0; k < KNN; ++k)
                a += sc[k] * inv * vproj[(size_t)(b*Jj + nbs[ri][k])*24 + h*3 + lane];
            P[((size_t)(b*Jj + ri))*32 + h*4 + lane] = a;
        }
    }
}

// ---------------------------------------------------------------------------
// coords[i][c] = relu( h0[i]·wsum[:,c] + sum_h P[i][h][c] ), c<3. 1 wave/row.
__global__ __launch_bounds__(64)
void coords_fin_kernel(const float* __restrict__ h0, const float* __restrict__ wsum,
                       const float* __restrict__ P, float* __restrict__ crd) {
    int row = blockIdx.x, lane = threadIdx.x;
    float4 hv = *(const float4*)&h0[(size_t)row*Cc + lane*4];
    float t0=0, t1=0, t2=0;
    const float hx[4] = {hv.x, hv.y, hv.z, hv.w};
    #pragma unroll
    for (int u = 0; u < 4; ++u) {
        int e = lane*4 + u;
        float4 wv = *(const float4*)&wsum[e*4];
        t0 += hx[u]*wv.x; t1 += hx[u]*wv.y; t2 += hx[u]*wv.z;
    }
    #pragma unroll
    for (int s = 1; s < 64; s <<= 1) {
        t0 += __shfl_xor(t0, s); t1 += __shfl_xor(t1, s); t2 += __shfl_xor(t2, s);
    }
    if (lane < 3) {
        float sk = (lane == 0) ? t0 : (lane == 1) ? t1 : t2;
        float ps = 0.0f;
        #pragma unroll
        for (int h = 0; h < Hh; ++h) ps += P[(size_t)row*32 + h*4 + lane];
        crd[(size_t)row*4 + lane] = fmaxf(sk + ps, 0.0f);
    }
}

// ---------------------------------------------------------------------------
// bf16 MFMA GEMM, B^T input ([N][K]), segmented A along K, fp32 accum.
template<int BM, int BN, int BK, int NSEG, bool RELU_STATS, bool OUT_BF16>
__global__ __launch_bounds__(256)
void gemm_bt_kernel(const unsigned short* __restrict__ A0, int lda0, int klen0,
                    const unsigned short* __restrict__ A1, int lda1, int klen1,
                    const unsigned short* __restrict__ A2, int lda2, int klen2,
                    const unsigned short* __restrict__ Bt, int ldb,
                    void* __restrict__ Cv, int ldc, float* __restrict__ stat) {
    constexpr int WM = BM/2, WN = BN/2;
    constexpr int MW = WM/16, NW = WN/16, KW = BK/32;
    constexpr int CHUNKA = BM*BK/8;
    constexpr int CHUNKB = BN*BK/8;
    constexpr int KB8 = BK/8;
    __shared__ unsigned short As[BM*BK];
    __shared__ unsigned short Bs[BN*BK];
    __shared__ float red[4];

    int tid = threadIdx.x;
    int wid = tid >> 6, lane = tid & 63;
    int wr = wid >> 1, wc = wid & 1;
    int bm = blockIdx.x * BM, bn = blockIdx.y * BN;

    f32x4 acc[MW][NW];
    #pragma unroll
    for (int m = 0; m < MW; ++m)
        #pragma unroll
        for (int n = 0; n < NW; ++n)
            acc[m][n] = (f32x4){0.f, 0.f, 0.f, 0.f};

    const unsigned short* Aseg[3] = {A0, A1, A2};
    const int ldas[3] = {lda0, lda1, lda2};
    const int klens[3] = {klen0, klen1, klen2};

    int kglob = 0;
    for (int seg = 0; seg < NSEG; ++seg) {
        const unsigned short* A = Aseg[seg];
        const int lda = ldas[seg];
        const int klen = klens[seg];
        for (int k0 = 0; k0 < klen; k0 += BK) {
            #pragma unroll
            for (int it = 0; it < CHUNKA/256; ++it) {
                int c = tid + it*256;
                int row = c / KB8, kp = c % KB8;
                __builtin_amdgcn_global_load_lds(
                    (const __attribute__((address_space(1))) unsigned int*)
                        (A + (size_t)(bm + row)*lda + k0 + kp*8),
                    (__attribute__((address_space(3))) unsigned int*)(As + c*8),
                    16, 0, 0);
            }
            #pragma unroll
            for (int it = 0; it < CHUNKB/256; ++it) {
                int c = tid + it*256;
                int row = c / KB8, kp = c % KB8;
                __builtin_amdgcn_global_load_lds(
                    (const __attribute__((address_space(1))) unsigned int*)
                        (Bt + (size_t)(bn + row)*ldb + kglob + k0 + kp*8),
                    (__attribute__((address_space(3))) unsigned int*)(Bs + c*8),
                    16, 0, 0);
            }
            __syncthreads();
            #pragma unroll
            for (int kp = 0; kp < KW; ++kp) {
                short8 af[MW], bf[NW];
                #pragma unroll
                for (int m = 0; m < MW; ++m)
                    af[m] = *(const short8*)&As[(wr*WM + m*16 + (lane & 15))*BK
                                               + kp*32 + (lane >> 4)*8];
                #pragma unroll
                for (int n = 0; n < NW; ++n)
                    bf[n] = *(const short8*)&Bs[(wc*WN + n*16 + (lane & 15))*BK
                                               + kp*32 + (lane >> 4)*8];
                #pragma unroll
                for (int m = 0; m < MW; ++m)
                    #pragma unroll
                    for (int n = 0; n < NW; ++n)
                        acc[m][n] = __builtin_amdgcn_mfma_f32_16x16x32_bf16(
                            af[m], bf[n], acc[m][n], 0, 0, 0);
            }
            __syncthreads();
        }
        kglob += klen;
    }

    int cr = (lane >> 4)*4, cc = lane & 15;
    float bsum = 0.0f;
    #pragma unroll
    for (int m = 0; m < MW; ++m)
        #pragma unroll
        for (int n = 0; n < NW; ++n)
            #pragma unroll
            for (int j = 0; j < 4; ++j) {
                float v = acc[m][n][j];
                if (RELU_STATS) { v = fmaxf(v, 0.0f); bsum += v; }
                size_t row = bm + wr*WM + m*16 + cr + j;
                size_t col = bn + wc*WN + n*16 + cc;
                if (OUT_BF16) ((unsigned short*)Cv)[row*ldc + col] = f2bf(v);
                else          ((float*)Cv)[row*ldc + col] = v;
            }
    if (RELU_STATS) {
        #pragma unroll
        for (int sft = 1; sft < 64; sft <<= 1) bsum += __shfl_xor(bsum, sft);
        if (lane == 0) red[wid] = bsum;
        __syncthreads();
        if (tid == 0) atomicAdd(stat, red[0] + red[1] + red[2] + red[3]);
    }
}

// ---------------------------------------------------------------------------
// attention (round-3 version): one wave per (row, head-pair); ushort8 loads.
__global__ __launch_bounds__(64)
void attn_kernel(const unsigned short* __restrict__ QKV,
                 const int* __restrict__ nbr, unsigned short* __restrict__ att) {
    int gid = blockIdx.x;
    int hp = gid & 3, row = gid >> 2, b = row / Jj;
    int lane = threadIdx.x;
    int h = hp*2 + (lane >> 5);
    int d0 = (lane & 31) * 8;

    u16x8 qu = *(const u16x8*)&QKV[(size_t)row*QKVN + h*Dd + d0];
    float qf[8];
    #pragma unroll
    for (int i = 0; i < 8; ++i) qf[i] = bf2f(qu[i]);
    const int* np_ = nbr + row * KNN;

    float sc[KNN]; int nb[KNN];
    #pragma unroll
    for (int k = 0; k < KNN; ++k) {
        int n = np_[k]; nb[k] = n;
        u16x8 ku = *(const u16x8*)&QKV[(size_t)(b*Jj + n)*QKVN + HD + h*Dd + d0];
        float p = 0;
        #pragma unroll
        for (int i = 0; i < 8; ++i) p += qf[i] * bf2f(ku[i]);
        #pragma unroll
        for (int s = 1; s < 32; s <<= 1) p += __shfl_xor(p, s);
        sc[k] = p;
    }
    float mx = -INFINITY;
    #pragma unroll
    for (int k = 0; k < KNN; ++k) {
        float s = sc[k] * 0.0625f;
        s = (s >= 0.0f) ? s : 0.2f * s;
        sc[k] = s; mx = fmaxf(mx, s);
    }
    float den = 0.0f;
    #pragma unroll
    for (int k = 0; k < KNN; ++k) { sc[k] = expf(sc[k] - mx); den += sc[k]; }
    float inv = 1.0f / den;
    float o[8] = {};
    #pragma unroll
    for (int k = 0; k < KNN; ++k) {
        u16x8 vu = *(const u16x8*)&QKV[(size_t)(b*Jj + nb[k])*QKVN + 2*HD + h*Dd + d0];
        float w = sc[k] * inv;
        #pragma unroll
        for (int i = 0; i < 8; ++i) o[i] += w * bf2f(vu[i]);
    }
    u16x8 ou;
    #pragma unroll
    for (int i = 0; i < 8; ++i) ou[i] = f2bf(o[i]);
    *(u16x8*)&att[(size_t)row*HD + h*Dd + d0] = ou;
}

// ---------------------------------------------------------------------------
__global__ __launch_bounds__(64)
void final_kernel(const float* __restrict__ h, const float* __restrict__ fcw,
                  const float* __restrict__ fcb, const float* __restrict__ stats,
                  float* __restrict__ out) {
    int row = blockIdx.x, lane = threadIdx.x;
    const float4 hv = *(const float4*)(h + (size_t)row*Cc + lane*4);
    float a0=0, a1=0, a2=0;
    const float hx[4] = {hv.x, hv.y, hv.z, hv.w};
    #pragma unroll
    for (int i = 0; i < 4; ++i) {
        int c = lane*4 + i;
        a0 += hx[i]*fcw[c*3+0]; a1 += hx[i]*fcw[c*3+1]; a2 += hx[i]*fcw[c*3+2];
    }
    #pragma unroll
    for (int s = 32; s > 0; s >>= 1) {
        a0 += __shfl_xor(a0, s); a1 += __shfl_xor(a1, s); a2 += __shfl_xor(a2, s);
    }
    if (lane == 0) {
        out[row*3+0] = a0 + fcb[0];
        out[row*3+1] = a1 + fcb[1];
        out[row*3+2] = a2 + fcb[2];
        if (row == 0)
            out[(size_t)Mrows*3] =
                (stats[0] + stats[1]) * (0.5f / ((float)Mrows * (float)Cc));
    }
}

// ---------------------------------------------------------------------------
extern "C" void kernel_launch(void* const* d_in, const int* in_sizes, int n_in,
                              void* d_out, int out_size, void* d_ws, size_t ws_size,
                              hipStream_t stream) {
    (void)in_sizes; (void)n_in; (void)out_size; (void)ws_size;
    const float* jf     = (const float*)d_in[0];
    const float* wq     = (const float*)d_in[1];
    const float* wk     = (const float*)d_in[2];
    const float* wv     = (const float*)d_in[3];
    const float* wp     = (const float*)d_in[4];
    const float* wsw    = (const float*)d_in[5];
    const float* wskip0 = (const float*)d_in[6];
    const float* fcw    = (const float*)d_in[7];
    const float* fcb    = (const float*)d_in[8];
    float* out = (float*)d_out;

    char* wsb = (char*)d_ws;
    unsigned short* QKVb  = (unsigned short*)(wsb + OFF_QKV);
    unsigned short* attb  = (unsigned short*)(wsb + OFF_ATT);
    float*          G     = (float*)(wsb + OFF_G);
    unsigned short* jfb   = (unsigned short*)(wsb + OFF_JFB);
    unsigned short* h1b   = (unsigned short*)(wsb + OFF_H1B);
    float*          h2f   = (float*)(wsb + OFF_H2F);
    unsigned short* wqkvT = (unsigned short*)(wsb + OFF_WQKVT);
    unsigned short* fbt   = (unsigned short*)(wsb + OFF_FBT);
    float*          Wvp   = (float*)(wsb + OFF_WVP);
    float*          vproj = (float*)(wsb + OFF_VPROJ);
    float*          P     = (float*)(wsb + OFF_P);
    float*          wsum  = (float*)(wsb + OFF_WSUM);
    float*          crd   = (float*)(wsb + OFF_CRD);
    int*            nbr0  = (int*)(wsb + OFF_NBR0);
    int*            nbr1  = (int*)(wsb + OFF_NBR1);
    float*          stats = (float*)(wsb + OFF_STAT);

    // ---- prep ----
    prep_weights_kernel<<<4353, 256, 0, stream>>>(wq, wk, wv, wp, wsw, wskip0,
                                                  wqkvT, fbt, stats, wsum);
    cvt_bf16_kernel<<<(Mrows*Cc/4 + 255)/256, 256, 0, stream>>>(jf, jfb, Mrows*Cc/4);
    g_gemm_kernel<<<dim3(4, 4, 8), 256, 0, stream>>>(wq, wk, G);
    wvp_kernel<<<8, 256, 0, stream>>>(wv, wp, Wvp);
    vproj_kernel<<<Mrows/8, 256, 0, stream>>>(jf, Wvp, vproj);

    // ---- layer 0 ----
    knn_kernel<<<Bb, 64, 0, stream>>>(jf, Cc, nbr0);
    score_kernel<<<Bb*Hh, 256, 0, stream>>>(jf, G, nbr0, vproj, P);
    coords_fin_kernel<<<Mrows, 64, 0, stream>>>(jf, wsum, P, crd);
    gemm_bt_kernel<128,128,64,1,false,true><<<dim3(Mrows/128, QKVN/128), 256, 0, stream>>>(
        jfb, Cc, Cc, jfb, Cc, 0, jfb, Cc, 0, wqkvT, Cc, QKVb, QKVN, nullptr);
    attn_kernel<<<Mrows*4, 64, 0, stream>>>(QKVb, nbr0, attb);
    gemm_bt_kernel<64,64,64,3,true,true><<<dim3(Mrows/64, Cc/64), 256, 0, stream>>>(
        attb, HD, HD, jfb, Cc, Cc, jfb, Cc, Cc, fbt, KFUSE, h1b, Cc, &stats[0]);

    // ---- layer 1 ----
    knn_kernel<<<Bb, 64, 0, stream>>>(crd, 4, nbr1);
    gemm_bt_kernel<128,128,64,1,false,true><<<dim3(Mrows/128, QKVN/128), 256, 0, stream>>>(
        h1b, Cc, Cc, h1b, Cc, 0, h1b, Cc, 0, wqkvT + (size_t)QKVN*Cc, Cc, QKVb, QKVN, nullptr);
    attn_kernel<<<Mrows*4, 64, 0, stream>>>(QKVb, nbr1, attb);
    gemm_bt_kernel<64,64,64,3,true,false><<<dim3(Mrows/64, Cc/64), 256, 0, stream>>>(
        attb, HD, HD, h1b, Cc, Cc, jfb, Cc, Cc, fbt + (size_t)Cc*KFUSE, KFUSE, h2f, Cc, &stats[1]);

    // ---- final ----
    final_kernel<<<Mrows, 64, 0, stream>>>(h2f, fcw, fcb, stats, out);
}

// Round 6
// 343.255 us; speedup vs baseline: 1.3115x; 1.2976x over previous
//
#include <hip/hip_runtime.h>
#include <hip/hip_bf16.h>
#include <math.h>

namespace {
constexpr int Bb = 256, Jj = 21, Cc = 256, Hh = 8, Dd = 256;
constexpr int Mrows = Bb * Jj;      // 5376
constexpr int HD    = Hh * Dd;      // 2048
constexpr int QKVN  = 3 * HD;       // 6144
constexpr int KNN   = 8;
constexpr int KFUSE = HD + Cc + Cc; // 2560

// ---- workspace byte offsets ----
constexpr size_t OFF_QKV   = 0;                                   // bf16 5376x6144
constexpr size_t OFF_ATT   = OFF_QKV   + (size_t)Mrows*QKVN*2;    // bf16 5376x2048
constexpr size_t OFF_T     = OFF_ATT   + (size_t)Mrows*HD*2;      // f32  5376x2048
constexpr size_t OFF_G     = OFF_T     + (size_t)Mrows*HD*4;      // f32  256x2048
constexpr size_t OFF_JFB   = OFF_G     + (size_t)Cc*HD*4;         // bf16 5376x256
constexpr size_t OFF_H1B   = OFF_JFB   + (size_t)Mrows*Cc*2;      // bf16 5376x256
constexpr size_t OFF_H2F   = OFF_H1B   + (size_t)Mrows*Cc*2;      // f32  5376x256
constexpr size_t OFF_WQKVT = OFF_H2F   + (size_t)Mrows*Cc*4;      // bf16 2x6144x256
constexpr size_t OFF_FBT   = OFF_WQKVT + (size_t)2*QKVN*Cc*2;     // bf16 2x256x2560
constexpr size_t OFF_WVP   = OFF_FBT   + (size_t)2*Cc*KFUSE*2;    // f32  256x24
constexpr size_t OFF_VPROJ = OFF_WVP   + (size_t)Cc*24*4;         // f32  5376x24
constexpr size_t OFF_WSUM  = OFF_VPROJ + (size_t)Mrows*24*4;      // f32  256x4
constexpr size_t OFF_CRD   = OFF_WSUM  + (size_t)Cc*4*4;          // f32  5376x4
constexpr size_t OFF_NBR0  = OFF_CRD   + (size_t)Mrows*4*4;       // int  5376x8
constexpr size_t OFF_NBR1  = OFF_NBR0  + (size_t)Mrows*KNN*4;
constexpr size_t OFF_STAT  = OFF_NBR1  + (size_t)Mrows*KNN*4;     // 2 f32
} // namespace

typedef short short8 __attribute__((ext_vector_type(8)));
typedef unsigned short u16x8 __attribute__((ext_vector_type(8)));
typedef float f32x4 __attribute__((ext_vector_type(4)));

__device__ __forceinline__ unsigned short f2bf(float x) {
    unsigned int u = __float_as_uint(x);
    u = u + 0x7fffu + ((u >> 16) & 1u);            // round-to-nearest-even
    return (unsigned short)(u >> 16);
}
__device__ __forceinline__ float bf2f(unsigned short b) {
    return __uint_as_float(((unsigned int)b) << 16);
}

// ---------------------------------------------------------------------------
// exact stable-argsort kNN: ranks 1..8 by (d2, index) ascending
__global__ __launch_bounds__(64)
void knn_kernel(const float* __restrict__ src, int ld, int* __restrict__ nbr) {
    int b = blockIdx.x;
    __shared__ float cs[Jj][3];
    int t = threadIdx.x;
    if (t < Jj) {
        const float* p = src + (size_t)(b * Jj + t) * ld;
        cs[t][0] = p[0]; cs[t][1] = p[1]; cs[t][2] = p[2];
    }
    __syncthreads();
    if (t < Jj) {
        float x = cs[t][0], y = cs[t][1], z = cs[t][2];
        float d2[Jj];
        #pragma unroll
        for (int jj = 0; jj < Jj; ++jj) {
            float dx = x - cs[jj][0], dy = y - cs[jj][1], dz = z - cs[jj][2];
            d2[jj] = dx*dx + dy*dy + dz*dz;
        }
        unsigned int used = 0u;
        int out_base = (b * Jj + t) * KNN;
        #pragma unroll
        for (int r = 0; r <= KNN; ++r) {
            int best = -1; float bd = INFINITY;
            #pragma unroll
            for (int jj = 0; jj < Jj; ++jj)
                if (!((used >> jj) & 1u) && d2[jj] < bd) { bd = d2[jj]; best = jj; }
            used |= (1u << best);
            if (r > 0) nbr[out_base + r - 1] = best;
        }
    }
}

// ---------------------------------------------------------------------------
// fp32 -> bf16 elementwise (n4 = n/4)
__global__ __launch_bounds__(256)
void cvt_bf16_kernel(const float* __restrict__ in, unsigned short* __restrict__ out, int n4) {
    int i = blockIdx.x * 256 + threadIdx.x;
    if (i < n4) {
        float4 v = ((const float4*)in)[i];
        ushort4 o; o.x = f2bf(v.x); o.y = f2bf(v.y); o.z = f2bf(v.z); o.w = f2bf(v.w);
        ((ushort4*)out)[i] = o;
    }
}

// ---------------------------------------------------------------------------
// All 12 weight transposes (fp32 [K][N] -> bf16 [N][K]) + stats zero + wsum.
__global__ __launch_bounds__(256)
void prep_weights_kernel(const float* __restrict__ wq, const float* __restrict__ wk,
                         const float* __restrict__ wv, const float* __restrict__ wp,
                         const float* __restrict__ wsw, const float* __restrict__ wsk,
                         unsigned short* __restrict__ wqkvT,
                         unsigned short* __restrict__ fbt, float* __restrict__ stats,
                         float* __restrict__ wsum) {
    int bid = blockIdx.x;
    if (bid == 4352) {       // wsum[e][c] = ws0[e][c] + wskip0[e][c], c<3
        int e = threadIdx.x;
        float4 o;
        o.x = wsw[(size_t)e*Dd + 0] + wsk[(size_t)e*Dd + 0];
        o.y = wsw[(size_t)e*Dd + 1] + wsk[(size_t)e*Dd + 1];
        o.z = wsw[(size_t)e*Dd + 2] + wsk[(size_t)e*Dd + 2];
        o.w = 0.0f;
        *(float4*)&wsum[e*4] = o;
        if (e < 2) stats[e] = 0.0f;
        return;
    }
    const float* src; unsigned short* dst;
    int ldin, ldout, tilesX, tile;
    constexpr size_t CH = (size_t)Cc * HD;
    if (bid < 3072) {
        int op = bid >> 9; tile = bid & 511; tilesX = 64;
        ldin = HD; ldout = Cc;
        const float* s3[3] = {wq, wk, wv};
        src = s3[op % 3] + (size_t)(op / 3) * CH;
        dst = wqkvT + (size_t)(op % 3) * HD * Cc + (size_t)(op / 3) * QKVN * Cc;
    } else if (bid < 4096) {
        int op = (bid - 3072) >> 9; tile = (bid - 3072) & 511; tilesX = 8;
        ldin = Cc; ldout = KFUSE;
        src = wp + (size_t)op * HD * Cc;
        dst = fbt + (size_t)op * Cc * KFUSE;
    } else {
        int q = bid - 4096; int op = q >> 6; tile = q & 63; tilesX = 8;
        ldin = Cc; ldout = KFUSE;
        const float* s4[4] = {wsw, wsw + (size_t)Cc * Cc, wsk, wsk};
        src = s4[op];
        dst = fbt + (size_t)(op & 1) * Cc * KFUSE + HD + (size_t)(op >> 1) * Cc;
    }
    int bx = tile % tilesX, by = tile / tilesX;
    int n0 = bx * 32, k0 = by * 32;

    __shared__ float t[32][33];
    int r = threadIdx.x >> 3, c4 = (threadIdx.x & 7) * 4;
    float4 v = *(const float4*)&src[(size_t)(k0 + r) * ldin + n0 + c4];
    t[r][c4+0] = v.x; t[r][c4+1] = v.y; t[r][c4+2] = v.z; t[r][c4+3] = v.w;
    __syncthreads();
    ushort4 o;
    o.x = f2bf(t[c4+0][r]); o.y = f2bf(t[c4+1][r]);
    o.z = f2bf(t[c4+2][r]); o.w = f2bf(t[c4+3][r]);
    *(ushort4*)&dst[(size_t)(n0 + r) * ldout + k0 + c4] = o;
}

// ---------------------------------------------------------------------------
// G[c][h*256+c'] = sum_d wq[c][h*256+d] * wk[c'][h*256+d] (fp32, exact path)
// BM=BN=64, BK=32, 4x4 microtile. grid (4,4,8)
__global__ __launch_bounds__(256)
void g_gemm_kernel(const float* __restrict__ wq, const float* __restrict__ wk,
                   float* __restrict__ G) {
    constexpr int LDR = 68;
    __shared__ float As[32][LDR];
    __shared__ float Ws[32][LDR];
    int h = blockIdx.z;
    int m0 = blockIdx.x * 64, n0 = blockIdx.y * 64;
    int tid = threadIdx.x;
    int ty = tid >> 4, tx = tid & 15;
    float acc[4][4] = {};
    for (int kb = 0; kb < 256; kb += 32) {
        #pragma unroll
        for (int it = 0; it < 2; ++it) {
            int c = tid + it * 256;
            int row = c >> 3, col = (c & 7) * 4;
            float4 v = *(const float4*)&wq[(size_t)(m0 + row)*HD + h*256 + kb + col];
            float4 u = *(const float4*)&wk[(size_t)(n0 + row)*HD + h*256 + kb + col];
            As[col+0][row] = v.x; As[col+1][row] = v.y;
            As[col+2][row] = v.z; As[col+3][row] = v.w;
            Ws[col+0][row] = u.x; Ws[col+1][row] = u.y;
            Ws[col+2][row] = u.z; Ws[col+3][row] = u.w;
        }
        __syncthreads();
        #pragma unroll
        for (int kk = 0; kk < 32; ++kk) {
            float4 a = *(const float4*)&As[kk][ty*4];
            float4 b = *(const float4*)&Ws[kk][tx*4];
            float av[4] = {a.x, a.y, a.z, a.w};
            float bv[4] = {b.x, b.y, b.z, b.w};
            #pragma unroll
            for (int i = 0; i < 4; ++i)
                #pragma unroll
                for (int j = 0; j < 4; ++j)
                    acc[i][j] += av[i] * bv[j];
        }
        __syncthreads();
    }
    #pragma unroll
    for (int i = 0; i < 4; ++i) {
        float4 o = {acc[i][0], acc[i][1], acc[i][2], acc[i][3]};
        *(float4*)&G[(size_t)(m0 + ty*4 + i)*HD + h*256 + n0 + tx*4] = o;
    }
}

// ---------------------------------------------------------------------------
// T = h0 @ G  (fp32, M=5376 N=2048 K=256). BM=64 BN=128 BK=32, 256 thr,
// 4x8 split microtile (rows ty*4 and 32+ty*4): A-reads broadcast, B-reads
// stride-4. Single-buffered LDS, grid (84,16).
__global__ __launch_bounds__(256)
void tgemm_kernel(const float* __restrict__ A, const float* __restrict__ W,
                  float* __restrict__ C) {
    __shared__ float As[32][68];
    __shared__ float Ws[32][132];
    int tid = threadIdx.x;
    int bm = blockIdx.x * 64, bn = blockIdx.y * 128;
    int ty = tid >> 5, tx = tid & 31;          // ty 0..7, tx 0..31
    int arow = tid >> 2, acol = (tid & 3) * 8; // A: 64x32, 8 floats/thread
    int brow = tid >> 3, bcol = (tid & 7) * 16;// B: 32x128, 16 floats/thread
    float acc[8][4] = {};

    for (int k0 = 0; k0 < Cc; k0 += 32) {
        float4 a0 = *(const float4*)&A[(size_t)(bm + arow)*Cc + k0 + acol];
        float4 a1 = *(const float4*)&A[(size_t)(bm + arow)*Cc + k0 + acol + 4];
        const float* wp_ = &W[(size_t)(k0 + brow)*HD + bn + bcol];
        float4 w0 = *(const float4*)(wp_ + 0);
        float4 w1 = *(const float4*)(wp_ + 4);
        float4 w2 = *(const float4*)(wp_ + 8);
        float4 w3 = *(const float4*)(wp_ + 12);
        As[acol+0][arow] = a0.x; As[acol+1][arow] = a0.y;
        As[acol+2][arow] = a0.z; As[acol+3][arow] = a0.w;
        As[acol+4][arow] = a1.x; As[acol+5][arow] = a1.y;
        As[acol+6][arow] = a1.z; As[acol+7][arow] = a1.w;
        *(float4*)&Ws[brow][bcol+0]  = w0;
        *(float4*)&Ws[brow][bcol+4]  = w1;
        *(float4*)&Ws[brow][bcol+8]  = w2;
        *(float4*)&Ws[brow][bcol+12] = w3;
        __syncthreads();
        #pragma unroll
        for (int kk = 0; kk < 32; ++kk) {
            float4 av0 = *(const float4*)&As[kk][ty*4];
            float4 av1 = *(const float4*)&As[kk][32 + ty*4];
            float4 bv  = *(const float4*)&Ws[kk][tx*4];
            float a8[8] = {av0.x,av0.y,av0.z,av0.w,av1.x,av1.y,av1.z,av1.w};
            float b4[4] = {bv.x,bv.y,bv.z,bv.w};
            #pragma unroll
            for (int i = 0; i < 8; ++i)
                #pragma unroll
                for (int j = 0; j < 4; ++j)
                    acc[i][j] += a8[i] * b4[j];
        }
        __syncthreads();
    }
    #pragma unroll
    for (int half = 0; half < 2; ++half)
        #pragma unroll
        for (int i = 0; i < 4; ++i) {
            float4 o = {acc[half*4+i][0], acc[half*4+i][1],
                        acc[half*4+i][2], acc[half*4+i][3]};
            *(float4*)&C[(size_t)(bm + half*32 + ty*4 + i)*HD + bn + tx*4] = o;
        }
}

// ---------------------------------------------------------------------------
// Wvp2[e][h*3+c] = sum_d wv[e][h*256+d] * wp[h*256+d][c].  grid (8), 256 thr
__global__ __launch_bounds__(256)
void wvp_kernel(const float* __restrict__ wv, const float* __restrict__ wp,
                float* __restrict__ Wvp2) {
    int h = blockIdx.x;
    __shared__ float wpc[256][3];
    int t = threadIdx.x;
    const float* p = &wp[(size_t)(h*256 + t) * Cc];
    wpc[t][0] = p[0]; wpc[t][1] = p[1]; wpc[t][2] = p[2];
    __syncthreads();
    const float* vr = &wv[(size_t)t*HD + h*256];
    float a0=0, a1=0, a2=0;
    for (int d = 0; d < 256; ++d) {
        float v = vr[d];
        a0 += v*wpc[d][0]; a1 += v*wpc[d][1]; a2 += v*wpc[d][2];
    }
    float* o = &Wvp2[(size_t)t*24 + h*3];
    o[0]=a0; o[1]=a1; o[2]=a2;
}

// ---------------------------------------------------------------------------
// vproj[j][o] = sum_e h0[j][e] * Wvp2[e][o], o<24.  8 rows/block, 256 thr.
__global__ __launch_bounds__(256)
void vproj_kernel(const float* __restrict__ h0, const float* __restrict__ Wvp2,
                  float* __restrict__ vproj) {
    __shared__ float hr[8][256];
    __shared__ float wl[6144];
    int t = threadIdx.x;
    int j0 = blockIdx.x * 8;
    #pragma unroll
    for (int i = 0; i < 6; ++i)
        *(float4*)&wl[t*4 + i*1024] = *(const float4*)&Wvp2[t*4 + i*1024];
    {
        int r = t >> 5, c = (t & 31) * 8;
        const float* src = &h0[(size_t)(j0 + r)*Cc + c];
        *(float4*)&hr[r][c]   = *(const float4*)src;
        *(float4*)&hr[r][c+4] = *(const float4*)(src + 4);
    }
    __syncthreads();
    int r = t >> 5, o = t & 31;
    if (o < 24) {
        float a = 0.0f;
        for (int e = 0; e < 256; ++e) a += hr[r][e] * wl[e*24 + o];
        vproj[(size_t)(j0 + r)*24 + o] = a;
    }
}

// ---------------------------------------------------------------------------
// precise layer-0 coords: per row i, softmax(leaky(T_i . h0_nbr /16)) over K,
// crd[i*4+c] = relu(sum_k w * vproj[nbr] + h0_i . wsum[:,c])
__global__ __launch_bounds__(64)
void precise_kernel(const float* __restrict__ T, const float* __restrict__ h0,
                    const int* __restrict__ nbr, const float* __restrict__ vproj,
                    const float* __restrict__ wsum, float* __restrict__ crd) {
    int i = blockIdx.x;
    int b = i / Jj;
    int l = threadIdx.x;
    __shared__ float Ts[8][260];
    __shared__ float nb[8][260];
    __shared__ float hi[256];
    #pragma unroll
    for (int u = 0; u < 8; ++u) {
        int idx = u*64 + l;
        float4 v = *(const float4*)&T[(size_t)i*HD + idx*4];
        int hh = idx >> 6, dd = (idx & 63) * 4;
        *(float4*)&Ts[hh][dd] = v;
    }
    *(float4*)&hi[l*4] = *(const float4*)&h0[(size_t)i*Cc + l*4];
    int kq = l >> 3, s = l & 7;
    int njs = nbr[i*KNN + kq];
    const float* nrow = &h0[(size_t)(b*Jj + njs)*Cc];
    #pragma unroll
    for (int u = 0; u < 8; ++u)
        *(float4*)&nb[kq][(s*8+u)*4] = *(const float4*)&nrow[(s*8+u)*4];
    __syncthreads();

    int k = l >> 3, h = l & 7;
    float sacc = 0;
    #pragma unroll 8
    for (int d = 0; d < 256; d += 4) {
        float4 tv = *(const float4*)&Ts[h][d];
        float4 nv = *(const float4*)&nb[k][d];
        sacc += tv.x*nv.x + tv.y*nv.y + tv.z*nv.z + tv.w*nv.w;
    }
    float sc = sacc * 0.0625f;
    sc = (sc >= 0.0f) ? sc : 0.2f * sc;
    float m = sc;
    m = fmaxf(m, __shfl_xor(m, 8));
    m = fmaxf(m, __shfl_xor(m, 16));
    m = fmaxf(m, __shfl_xor(m, 32));
    float e = expf(sc - m);
    float den = e;
    den += __shfl_xor(den, 8); den += __shfl_xor(den, 16); den += __shfl_xor(den, 32);
    float w = e / den;

    int njk = nbr[i*KNN + k];
    const float* vp = &vproj[(size_t)(b*Jj + njk)*24 + h*3];
    float t0 = w * vp[0], t1 = w * vp[1], t2 = w * vp[2];
    #pragma unroll
    for (int u = 0; u < 4; ++u) {
        int e4 = l*4 + u;
        float hv = hi[e4];
        float4 wv = *(const float4*)&wsum[e4*4];
        t0 += hv * wv.x; t1 += hv * wv.y; t2 += hv * wv.z;
    }
    #pragma unroll
    for (int sft = 1; sft < 64; sft <<= 1) {
        t0 += __shfl_xor(t0, sft); t1 += __shfl_xor(t1, sft); t2 += __shfl_xor(t2, sft);
    }
    if (l == 0) {
        crd[i*4+0] = fmaxf(t0, 0.0f);
        crd[i*4+1] = fmaxf(t1, 0.0f);
        crd[i*4+2] = fmaxf(t2, 0.0f);
        crd[i*4+3] = 0.0f;
    }
}

// ---------------------------------------------------------------------------
// bf16 MFMA GEMM, B^T input ([N][K]), segmented A along K, fp32 accum.
template<int BM, int BN, int BK, int NSEG, bool RELU_STATS, bool OUT_BF16>
__global__ __launch_bounds__(256)
void gemm_bt_kernel(const unsigned short* __restrict__ A0, int lda0, int klen0,
                    const unsigned short* __restrict__ A1, int lda1, int klen1,
                    const unsigned short* __restrict__ A2, int lda2, int klen2,
                    const unsigned short* __restrict__ Bt, int ldb,
                    void* __restrict__ Cv, int ldc, float* __restrict__ stat) {
    constexpr int WM = BM/2, WN = BN/2;
    constexpr int MW = WM/16, NW = WN/16, KW = BK/32;
    constexpr int CHUNKA = BM*BK/8;
    constexpr int CHUNKB = BN*BK/8;
    constexpr int KB8 = BK/8;
    __shared__ unsigned short As[BM*BK];
    __shared__ unsigned short Bs[BN*BK];
    __shared__ float red[4];

    int tid = threadIdx.x;
    int wid = tid >> 6, lane = tid & 63;
    int wr = wid >> 1, wc = wid & 1;
    int bm = blockIdx.x * BM, bn = blockIdx.y * BN;

    f32x4 acc[MW][NW];
    #pragma unroll
    for (int m = 0; m < MW; ++m)
        #pragma unroll
        for (int n = 0; n < NW; ++n)
            acc[m][n] = (f32x4){0.f, 0.f, 0.f, 0.f};

    const unsigned short* Aseg[3] = {A0, A1, A2};
    const int ldas[3] = {lda0, lda1, lda2};
    const int klens[3] = {klen0, klen1, klen2};

    int kglob = 0;
    for (int seg = 0; seg < NSEG; ++seg) {
        const unsigned short* A = Aseg[seg];
        const int lda = ldas[seg];
        const int klen = klens[seg];
        for (int k0 = 0; k0 < klen; k0 += BK) {
            #pragma unroll
            for (int it = 0; it < CHUNKA/256; ++it) {
                int c = tid + it*256;
                int row = c / KB8, kp = c % KB8;
                __builtin_amdgcn_global_load_lds(
                    (const __attribute__((address_space(1))) unsigned int*)
                        (A + (size_t)(bm + row)*lda + k0 + kp*8),
                    (__attribute__((address_space(3))) unsigned int*)(As + c*8),
                    16, 0, 0);
            }
            #pragma unroll
            for (int it = 0; it < CHUNKB/256; ++it) {
                int c = tid + it*256;
                int row = c / KB8, kp = c % KB8;
                __builtin_amdgcn_global_load_lds(
                    (const __attribute__((address_space(1))) unsigned int*)
                        (Bt + (size_t)(bn + row)*ldb + kglob + k0 + kp*8),
                    (__attribute__((address_space(3))) unsigned int*)(Bs + c*8),
                    16, 0, 0);
            }
            __syncthreads();
            #pragma unroll
            for (int kp = 0; kp < KW; ++kp) {
                short8 af[MW], bf[NW];
                #pragma unroll
                for (int m = 0; m < MW; ++m)
                    af[m] = *(const short8*)&As[(wr*WM + m*16 + (lane & 15))*BK
                                               + kp*32 + (lane >> 4)*8];
                #pragma unroll
                for (int n = 0; n < NW; ++n)
                    bf[n] = *(const short8*)&Bs[(wc*WN + n*16 + (lane & 15))*BK
                                               + kp*32 + (lane >> 4)*8];
                #pragma unroll
                for (int m = 0; m < MW; ++m)
                    #pragma unroll
                    for (int n = 0; n < NW; ++n)
                        acc[m][n] = __builtin_amdgcn_mfma_f32_16x16x32_bf16(
                            af[m], bf[n], acc[m][n], 0, 0, 0);
            }
            __syncthreads();
        }
        kglob += klen;
    }

    int cr = (lane >> 4)*4, cc = lane & 15;
    float bsum = 0.0f;
    #pragma unroll
    for (int m = 0; m < MW; ++m)
        #pragma unroll
        for (int n = 0; n < NW; ++n)
            #pragma unroll
            for (int j = 0; j < 4; ++j) {
                float v = acc[m][n][j];
                if (RELU_STATS) { v = fmaxf(v, 0.0f); bsum += v; }
                size_t row = bm + wr*WM + m*16 + cr + j;
                size_t col = bn + wc*WN + n*16 + cc;
                if (OUT_BF16) ((unsigned short*)Cv)[row*ldc + col] = f2bf(v);
                else          ((float*)Cv)[row*ldc + col] = v;
            }
    if (RELU_STATS) {
        #pragma unroll
        for (int sft = 1; sft < 64; sft <<= 1) bsum += __shfl_xor(bsum, sft);
        if (lane == 0) red[wid] = bsum;
        __syncthreads();
        if (tid == 0) atomicAdd(stat, red[0] + red[1] + red[2] + red[3]);
    }
}

// ---------------------------------------------------------------------------
// attention: one wave per (row, head-pair); 32 lanes per head, ushort8 loads.
__global__ __launch_bounds__(64)
void attn_kernel(const unsigned short* __restrict__ QKV,
                 const int* __restrict__ nbr, unsigned short* __restrict__ att) {
    int gid = blockIdx.x;
    int hp = gid & 3, row = gid >> 2, b = row / Jj;
    int lane = threadIdx.x;
    int h = hp*2 + (lane >> 5);
    int d0 = (lane & 31) * 8;

    u16x8 qu = *(const u16x8*)&QKV[(size_t)row*QKVN + h*Dd + d0];
    float qf[8];
    #pragma unroll
    for (int i = 0; i < 8; ++i) qf[i] = bf2f(qu[i]);
    const int* np_ = nbr + row * KNN;

    float sc[KNN]; int nb[KNN];
    #pragma unroll
    for (int k = 0; k < KNN; ++k) {
        int n = np_[k]; nb[k] = n;
        u16x8 ku = *(const u16x8*)&QKV[(size_t)(b*Jj + n)*QKVN + HD + h*Dd + d0];
        float p = 0;
        #pragma unroll
        for (int i = 0; i < 8; ++i) p += qf[i] * bf2f(ku[i]);
        #pragma unroll
        for (int s = 1; s < 32; s <<= 1) p += __shfl_xor(p, s);
        sc[k] = p;
    }
    float mx = -INFINITY;
    #pragma unroll
    for (int k = 0; k < KNN; ++k) {
        float s = sc[k] * 0.0625f;
        s = (s >= 0.0f) ? s : 0.2f * s;
        sc[k] = s; mx = fmaxf(mx, s);
    }
    float den = 0.0f;
    #pragma unroll
    for (int k = 0; k < KNN; ++k) { sc[k] = expf(sc[k] - mx); den += sc[k]; }
    float inv = 1.0f / den;
    float o[8] = {};
    #pragma unroll
    for (int k = 0; k < KNN; ++k) {
        u16x8 vu = *(const u16x8*)&QKV[(size_t)(b*Jj + nb[k])*QKVN + 2*HD + h*Dd + d0];
        float w = sc[k] * inv;
        #pragma unroll
        for (int i = 0; i < 8; ++i) o[i] += w * bf2f(vu[i]);
    }
    u16x8 ou;
    #pragma unroll
    for (int i = 0; i < 8; ++i) ou[i] = f2bf(o[i]);
    *(u16x8*)&att[(size_t)row*HD + h*Dd + d0] = ou;
}

// ---------------------------------------------------------------------------
__global__ __launch_bounds__(64)
void final_kernel(const float* __restrict__ h, const float* __restrict__ fcw,
                  const float* __restrict__ fcb, const float* __restrict__ stats,
                  float* __restrict__ out) {
    int row = blockIdx.x, lane = threadIdx.x;
    const float4 hv = *(const float4*)(h + (size_t)row*Cc + lane*4);
    float a0=0, a1=0, a2=0;
    const float hx[4] = {hv.x, hv.y, hv.z, hv.w};
    #pragma unroll
    for (int i = 0; i < 4; ++i) {
        int c = lane*4 + i;
        a0 += hx[i]*fcw[c*3+0]; a1 += hx[i]*fcw[c*3+1]; a2 += hx[i]*fcw[c*3+2];
    }
    #pragma unroll
    for (int s = 32; s > 0; s >>= 1) {
        a0 += __shfl_xor(a0, s); a1 += __shfl_xor(a1, s); a2 += __shfl_xor(a2, s);
    }
    if (lane == 0) {
        out[row*3+0] = a0 + fcb[0];
        out[row*3+1] = a1 + fcb[1];
        out[row*3+2] = a2 + fcb[2];
        if (row == 0)
            out[(size_t)Mrows*3] =
                (stats[0] + stats[1]) * (0.5f / ((float)Mrows * (float)Cc));
    }
}

// ---------------------------------------------------------------------------
extern "C" void kernel_launch(void* const* d_in, const int* in_sizes, int n_in,
                              void* d_out, int out_size, void* d_ws, size_t ws_size,
                              hipStream_t stream) {
    (void)in_sizes; (void)n_in; (void)out_size; (void)ws_size;
    const float* jf     = (const float*)d_in[0];
    const float* wq     = (const float*)d_in[1];
    const float* wk     = (const float*)d_in[2];
    const float* wv     = (const float*)d_in[3];
    const float* wp     = (const float*)d_in[4];
    const float* wsw    = (const float*)d_in[5];
    const float* wskip0 = (const float*)d_in[6];
    const float* fcw    = (const float*)d_in[7];
    const float* fcb    = (const float*)d_in[8];
    float* out = (float*)d_out;

    char* wsb = (char*)d_ws;
    unsigned short* QKVb  = (unsigned short*)(wsb + OFF_QKV);
    unsigned short* attb  = (unsigned short*)(wsb + OFF_ATT);
    float*          Tm    = (float*)(wsb + OFF_T);
    float*          G     = (float*)(wsb + OFF_G);
    unsigned short* jfb   = (unsigned short*)(wsb + OFF_JFB);
    unsigned short* h1b   = (unsigned short*)(wsb + OFF_H1B);
    float*          h2f   = (float*)(wsb + OFF_H2F);
    unsigned short* wqkvT = (unsigned short*)(wsb + OFF_WQKVT);
    unsigned short* fbt   = (unsigned short*)(wsb + OFF_FBT);
    float*          Wvp   = (float*)(wsb + OFF_WVP);
    float*          vproj = (float*)(wsb + OFF_VPROJ);
    float*          wsum  = (float*)(wsb + OFF_WSUM);
    float*          crd   = (float*)(wsb + OFF_CRD);
    int*            nbr0  = (int*)(wsb + OFF_NBR0);
    int*            nbr1  = (int*)(wsb + OFF_NBR1);
    float*          stats = (float*)(wsb + OFF_STAT);

    // ---- prep ----
    prep_weights_kernel<<<4353, 256, 0, stream>>>(wq, wk, wv, wp, wsw, wskip0,
                                                  wqkvT, fbt, stats, wsum);
    cvt_bf16_kernel<<<(Mrows*Cc/4 + 255)/256, 256, 0, stream>>>(jf, jfb, Mrows*Cc/4);
    g_gemm_kernel<<<dim3(4, 4, 8), 256, 0, stream>>>(wq, wk, G);
    tgemm_kernel<<<dim3(Mrows/64, HD/128), 256, 0, stream>>>(jf, G, Tm);
    wvp_kernel<<<8, 256, 0, stream>>>(wv, wp, Wvp);
    vproj_kernel<<<Mrows/8, 256, 0, stream>>>(jf, Wvp, vproj);

    // ---- layer 0 ----
    knn_kernel<<<Bb, 64, 0, stream>>>(jf, Cc, nbr0);
    precise_kernel<<<Mrows, 64, 0, stream>>>(Tm, jf, nbr0, vproj, wsum, crd);
    gemm_bt_kernel<128,128,64,1,false,true><<<dim3(Mrows/128, QKVN/128), 256, 0, stream>>>(
        jfb, Cc, Cc, jfb, Cc, 0, jfb, Cc, 0, wqkvT, Cc, QKVb, QKVN, nullptr);
    attn_kernel<<<Mrows*4, 64, 0, stream>>>(QKVb, nbr0, attb);
    gemm_bt_kernel<64,64,64,3,true,true><<<dim3(Mrows/64, Cc/64), 256, 0, stream>>>(
        attb, HD, HD, jfb, Cc, Cc, jfb, Cc, Cc, fbt, KFUSE, h1b, Cc, &stats[0]);

    // ---- layer 1 ----
    knn_kernel<<<Bb, 64, 0, stream>>>(crd, 4, nbr1);
    gemm_bt_kernel<128,128,64,1,false,true><<<dim3(Mrows/128, QKVN/128), 256, 0, stream>>>(
        h1b, Cc, Cc, h1b, Cc, 0, h1b, Cc, 0, wqkvT + (size_t)QKVN*Cc, Cc, QKVb, QKVN, nullptr);
    attn_kernel<<<Mrows*4, 64, 0, stream>>>(QKVb, nbr1, attb);
    gemm_bt_kernel<64,64,64,3,true,false><<<dim3(Mrows/64, Cc/64), 256, 0, stream>>>(
        attb, HD, HD, h1b, Cc, Cc, jfb, Cc, Cc, fbt + (size_t)Cc*KFUSE, KFUSE, h2f, Cc, &stats[1]);

    // ---- final ----
    final_kernel<<<Mrows, 64, 0, stream>>>(h2f, fcw, fcb, stats, out);
}

// Round 7
// 313.620 us; speedup vs baseline: 1.4354x; 1.0945x over previous
//
#include <hip/hip_runtime.h>
#include <hip/hip_bf16.h>
#include <math.h>
#include <type_traits>

namespace {
constexpr int Bb = 256, Jj = 21, Cc = 256, Hh = 8, Dd = 256;
constexpr int Mrows = Bb * Jj;      // 5376
constexpr int HD    = Hh * Dd;      // 2048
constexpr int QKVN  = 3 * HD;       // 6144
constexpr int KNN   = 8;
constexpr int KFUSE = HD + Cc + Cc; // 2560

// ---- workspace byte offsets ----
// T (f32 5376x2048 = 44MB) aliases the QKV region (66MB): T is fully dead
// before the QKV gemm writes (precise_kernel consumes it earlier in-stream).
constexpr size_t OFF_QKV   = 0;                                   // bf16 5376x6144
constexpr size_t OFF_T     = 0;                                   // f32  5376x2048 (alias)
constexpr size_t OFF_ATT   = OFF_QKV   + (size_t)Mrows*QKVN*2;    // bf16 5376x2048
constexpr size_t OFF_GT    = OFF_ATT   + (size_t)Mrows*HD*2;      // f16  2048x768
constexpr size_t OFF_JFB   = OFF_GT    + (size_t)HD*768*2;        // bf16 5376x256
constexpr size_t OFF_JFH   = OFF_JFB   + (size_t)Mrows*Cc*2;      // f16  5376x256
constexpr size_t OFF_JFL   = OFF_JFH   + (size_t)Mrows*Cc*2;      // f16  5376x256
constexpr size_t OFF_JFD   = OFF_JFL   + (size_t)Mrows*Cc*2;      // f16  5376x256
constexpr size_t OFF_H1B   = OFF_JFD   + (size_t)Mrows*Cc*2;      // bf16 5376x256
constexpr size_t OFF_H2F   = OFF_H1B   + (size_t)Mrows*Cc*2;      // f32  5376x256
constexpr size_t OFF_WQKVT = OFF_H2F   + (size_t)Mrows*Cc*4;      // bf16 2x6144x256
constexpr size_t OFF_FBT   = OFF_WQKVT + (size_t)2*QKVN*Cc*2;     // bf16 2x256x2560
constexpr size_t OFF_WVP   = OFF_FBT   + (size_t)2*Cc*KFUSE*2;    // f32  256x24
constexpr size_t OFF_VPROJ = OFF_WVP   + (size_t)Cc*24*4;         // f32  5376x24
constexpr size_t OFF_WSUM  = OFF_VPROJ + (size_t)Mrows*24*4;      // f32  256x4
constexpr size_t OFF_CRD   = OFF_WSUM  + (size_t)Cc*4*4;          // f32  5376x4
constexpr size_t OFF_NBR0  = OFF_CRD   + (size_t)Mrows*4*4;       // int  5376x8
constexpr size_t OFF_NBR1  = OFF_NBR0  + (size_t)Mrows*KNN*4;
constexpr size_t OFF_STAT  = OFF_NBR1  + (size_t)Mrows*KNN*4;     // 2 f32
} // namespace

typedef short short8 __attribute__((ext_vector_type(8)));
typedef _Float16 half8 __attribute__((ext_vector_type(8)));
typedef _Float16 half4v __attribute__((ext_vector_type(4)));
typedef unsigned short u16x8 __attribute__((ext_vector_type(8)));
typedef float f32x4 __attribute__((ext_vector_type(4)));

__device__ __forceinline__ unsigned short f2bf(float x) {
    unsigned int u = __float_as_uint(x);
    u = u + 0x7fffu + ((u >> 16) & 1u);            // round-to-nearest-even
    return (unsigned short)(u >> 16);
}
__device__ __forceinline__ float bf2f(unsigned short b) {
    return __uint_as_float(((unsigned int)b) << 16);
}

// ---------------------------------------------------------------------------
// exact stable-argsort kNN: ranks 1..8 by (d2, index) ascending
__global__ __launch_bounds__(64)
void knn_kernel(const float* __restrict__ src, int ld, int* __restrict__ nbr) {
    int b = blockIdx.x;
    __shared__ float cs[Jj][3];
    int t = threadIdx.x;
    if (t < Jj) {
        const float* p = src + (size_t)(b * Jj + t) * ld;
        cs[t][0] = p[0]; cs[t][1] = p[1]; cs[t][2] = p[2];
    }
    __syncthreads();
    if (t < Jj) {
        float x = cs[t][0], y = cs[t][1], z = cs[t][2];
        float d2[Jj];
        #pragma unroll
        for (int jj = 0; jj < Jj; ++jj) {
            float dx = x - cs[jj][0], dy = y - cs[jj][1], dz = z - cs[jj][2];
            d2[jj] = dx*dx + dy*dy + dz*dz;
        }
        unsigned int used = 0u;
        int out_base = (b * Jj + t) * KNN;
        #pragma unroll
        for (int r = 0; r <= KNN; ++r) {
            int best = -1; float bd = INFINITY;
            #pragma unroll
            for (int jj = 0; jj < Jj; ++jj)
                if (!((used >> jj) & 1u) && d2[jj] < bd) { bd = d2[jj]; best = jj; }
            used |= (1u << best);
            if (r > 0) nbr[out_base + r - 1] = best;
        }
    }
}

// ---------------------------------------------------------------------------
// fp32 -> bf16 + fp16 3-way split (hi, 16*lo, x/128), vectorized x4
__global__ __launch_bounds__(256)
void cvt_split_kernel(const float* __restrict__ in, unsigned short* __restrict__ outB,
                      _Float16* __restrict__ outH, _Float16* __restrict__ outL,
                      _Float16* __restrict__ outD, int n4) {
    int i = blockIdx.x * 256 + threadIdx.x;
    if (i < n4) {
        float4 v = ((const float4*)in)[i];
        float x[4] = {v.x, v.y, v.z, v.w};
        ushort4 ob; half4v oh, ol, od;
        #pragma unroll
        for (int u = 0; u < 4; ++u) {
            ((unsigned short*)&ob)[u] = f2bf(x[u]);
            _Float16 h = (_Float16)x[u];
            oh[u] = h;
            ol[u] = (_Float16)((x[u] - (float)h) * 16.0f);
            od[u] = (_Float16)(x[u] * 0.0078125f);   // /128
        }
        ((ushort4*)outB)[i] = ob;
        ((half4v*)outH)[i] = oh;
        ((half4v*)outL)[i] = ol;
        ((half4v*)outD)[i] = od;
    }
}

// ---------------------------------------------------------------------------
// All 12 weight transposes (fp32 [K][N] -> bf16 [N][K]) + stats zero + wsum.
__global__ __launch_bounds__(256)
void prep_weights_kernel(const float* __restrict__ wq, const float* __restrict__ wk,
                         const float* __restrict__ wv, const float* __restrict__ wp,
                         const float* __restrict__ wsw, const float* __restrict__ wsk,
                         unsigned short* __restrict__ wqkvT,
                         unsigned short* __restrict__ fbt, float* __restrict__ stats,
                         float* __restrict__ wsum) {
    int bid = blockIdx.x;
    if (bid == 4352) {       // wsum[e][c] = ws0[e][c] + wskip0[e][c], c<3
        int e = threadIdx.x;
        float4 o;
        o.x = wsw[(size_t)e*Dd + 0] + wsk[(size_t)e*Dd + 0];
        o.y = wsw[(size_t)e*Dd + 1] + wsk[(size_t)e*Dd + 1];
        o.z = wsw[(size_t)e*Dd + 2] + wsk[(size_t)e*Dd + 2];
        o.w = 0.0f;
        *(float4*)&wsum[e*4] = o;
        if (e < 2) stats[e] = 0.0f;
        return;
    }
    const float* src; unsigned short* dst;
    int ldin, ldout, tilesX, tile;
    constexpr size_t CH = (size_t)Cc * HD;
    if (bid < 3072) {
        int op = bid >> 9; tile = bid & 511; tilesX = 64;
        ldin = HD; ldout = Cc;
        const float* s3[3] = {wq, wk, wv};
        src = s3[op % 3] + (size_t)(op / 3) * CH;
        dst = wqkvT + (size_t)(op % 3) * HD * Cc + (size_t)(op / 3) * QKVN * Cc;
    } else if (bid < 4096) {
        int op = (bid - 3072) >> 9; tile = (bid - 3072) & 511; tilesX = 8;
        ldin = Cc; ldout = KFUSE;
        src = wp + (size_t)op * HD * Cc;
        dst = fbt + (size_t)op * Cc * KFUSE;
    } else {
        int q = bid - 4096; int op = q >> 6; tile = q & 63; tilesX = 8;
        ldin = Cc; ldout = KFUSE;
        const float* s4[4] = {wsw, wsw + (size_t)Cc * Cc, wsk, wsk};
        src = s4[op];
        dst = fbt + (size_t)(op & 1) * Cc * KFUSE + HD + (size_t)(op >> 1) * Cc;
    }
    int bx = tile % tilesX, by = tile / tilesX;
    int n0 = bx * 32, k0 = by * 32;

    __shared__ float t[32][33];
    int r = threadIdx.x >> 3, c4 = (threadIdx.x & 7) * 4;
    float4 v = *(const float4*)&src[(size_t)(k0 + r) * ldin + n0 + c4];
    t[r][c4+0] = v.x; t[r][c4+1] = v.y; t[r][c4+2] = v.z; t[r][c4+3] = v.w;
    __syncthreads();
    ushort4 o;
    o.x = f2bf(t[c4+0][r]); o.y = f2bf(t[c4+1][r]);
    o.z = f2bf(t[c4+2][r]); o.w = f2bf(t[c4+3][r]);
    *(ushort4*)&dst[(size_t)(n0 + r) * ldout + k0 + c4] = o;
}

// ---------------------------------------------------------------------------
// G_h = wq_h @ wk_h^T (fp32 accum), emitted directly as fp16-split B^T panels:
// GT[n = h*256+c'][k] with k in [0,256)=fp16(G), [256,512)=fp16(G/16),
// [512,768)=fp16(128*(G - fp16(G))).  BM=BN=64, BK=32. grid (4,4,8)
__global__ __launch_bounds__(256)
void g_gemm_kernel(const float* __restrict__ wq, const float* __restrict__ wk,
                   _Float16* __restrict__ GT) {
    constexpr int LDR = 68;
    __shared__ float As[32][LDR];
    __shared__ float Ws[32][LDR];
    int h = blockIdx.z;
    int m0 = blockIdx.x * 64, n0 = blockIdx.y * 64;
    int tid = threadIdx.x;
    int ty = tid >> 4, tx = tid & 15;
    float acc[4][4] = {};
    for (int kb = 0; kb < 256; kb += 32) {
        #pragma unroll
        for (int it = 0; it < 2; ++it) {
            int c = tid + it * 256;
            int row = c >> 3, col = (c & 7) * 4;
            float4 v = *(const float4*)&wq[(size_t)(m0 + row)*HD + h*256 + kb + col];
            float4 u = *(const float4*)&wk[(size_t)(n0 + row)*HD + h*256 + kb + col];
            As[col+0][row] = v.x; As[col+1][row] = v.y;
            As[col+2][row] = v.z; As[col+3][row] = v.w;
            Ws[col+0][row] = u.x; Ws[col+1][row] = u.y;
            Ws[col+2][row] = u.z; Ws[col+3][row] = u.w;
        }
        __syncthreads();
        #pragma unroll
        for (int kk = 0; kk < 32; ++kk) {
            float4 a = *(const float4*)&As[kk][ty*4];
            float4 b = *(const float4*)&Ws[kk][tx*4];
            float av[4] = {a.x, a.y, a.z, a.w};
            float bv[4] = {b.x, b.y, b.z, b.w};
            #pragma unroll
            for (int i = 0; i < 4; ++i)
                #pragma unroll
                for (int j = 0; j < 4; ++j)
                    acc[i][j] += av[i] * bv[j];
        }
        __syncthreads();
    }
    // transposed fp16-split epilogue: n = h*256+n0+tx*4+j, k = m0+ty*4+i
    #pragma unroll
    for (int j = 0; j < 4; ++j) {
        int n = h*256 + n0 + tx*4 + j;
        half4v hi, hs, lo;
        #pragma unroll
        for (int i = 0; i < 4; ++i) {
            float g = acc[i][j];
            _Float16 gh = (_Float16)g;
            hi[i] = gh;
            hs[i] = (_Float16)(g * 0.0625f);
            lo[i] = (_Float16)((g - (float)gh) * 128.0f);
        }
        _Float16* base = &GT[(size_t)n*768 + m0 + ty*4];
        *(half4v*)(base)       = hi;
        *(half4v*)(base + 256) = hs;
        *(half4v*)(base + 512) = lo;
    }
}

// ---------------------------------------------------------------------------
// Wvp2[e][h*3+c] = sum_d wv[e][h*256+d] * wp[h*256+d][c].  grid (8), 256 thr
__global__ __launch_bounds__(256)
void wvp_kernel(const float* __restrict__ wv, const float* __restrict__ wp,
                float* __restrict__ Wvp2) {
    int h = blockIdx.x;
    __shared__ float wpc[256][3];
    int t = threadIdx.x;
    const float* p = &wp[(size_t)(h*256 + t) * Cc];
    wpc[t][0] = p[0]; wpc[t][1] = p[1]; wpc[t][2] = p[2];
    __syncthreads();
    const float* vr = &wv[(size_t)t*HD + h*256];
    float a0=0, a1=0, a2=0;
    for (int d = 0; d < 256; ++d) {
        float v = vr[d];
        a0 += v*wpc[d][0]; a1 += v*wpc[d][1]; a2 += v*wpc[d][2];
    }
    float* o = &Wvp2[(size_t)t*24 + h*3];
    o[0]=a0; o[1]=a1; o[2]=a2;
}

// ---------------------------------------------------------------------------
// vproj[j][o] = sum_e h0[j][e] * Wvp2[e][o], o<24.  8 rows/block, 256 thr.
__global__ __launch_bounds__(256)
void vproj_kernel(const float* __restrict__ h0, const float* __restrict__ Wvp2,
                  float* __restrict__ vproj) {
    __shared__ float hr[8][256];
    __shared__ float wl[6144];
    int t = threadIdx.x;
    int j0 = blockIdx.x * 8;
    #pragma unroll
    for (int i = 0; i < 6; ++i)
        *(float4*)&wl[t*4 + i*1024] = *(const float4*)&Wvp2[t*4 + i*1024];
    {
        int r = t >> 5, c = (t & 31) * 8;
        const float* src = &h0[(size_t)(j0 + r)*Cc + c];
        *(float4*)&hr[r][c]   = *(const float4*)src;
        *(float4*)&hr[r][c+4] = *(const float4*)(src + 4);
    }
    __syncthreads();
    int r = t >> 5, o = t & 31;
    if (o < 24) {
        float a = 0.0f;
        for (int e = 0; e < 256; ++e) a += hr[r][e] * wl[e*24 + o];
        vproj[(size_t)(j0 + r)*24 + o] = a;
    }
}

// ---------------------------------------------------------------------------
// precise layer-0 coords: per row i, softmax(leaky(T_i . h0_nbr /16)) over K,
// crd[i*4+c] = relu(sum_k w * vproj[nbr] + h0_i . wsum[:,c])
__global__ __launch_bounds__(64)
void precise_kernel(const float* __restrict__ T, const float* __restrict__ h0,
                    const int* __restrict__ nbr, const float* __restrict__ vproj,
                    const float* __restrict__ wsum, float* __restrict__ crd) {
    int i = blockIdx.x;
    int b = i / Jj;
    int l = threadIdx.x;
    __shared__ float Ts[8][260];
    __shared__ float nb[8][260];
    __shared__ float hi[256];
    #pragma unroll
    for (int u = 0; u < 8; ++u) {
        int idx = u*64 + l;
        float4 v = *(const float4*)&T[(size_t)i*HD + idx*4];
        int hh = idx >> 6, dd = (idx & 63) * 4;
        *(float4*)&Ts[hh][dd] = v;
    }
    *(float4*)&hi[l*4] = *(const float4*)&h0[(size_t)i*Cc + l*4];
    int kq = l >> 3, s = l & 7;
    int njs = nbr[i*KNN + kq];
    const float* nrow = &h0[(size_t)(b*Jj + njs)*Cc];
    #pragma unroll
    for (int u = 0; u < 8; ++u)
        *(float4*)&nb[kq][(s*8+u)*4] = *(const float4*)&nrow[(s*8+u)*4];
    __syncthreads();

    int k = l >> 3, h = l & 7;
    float sacc = 0;
    #pragma unroll 8
    for (int d = 0; d < 256; d += 4) {
        float4 tv = *(const float4*)&Ts[h][d];
        float4 nv = *(const float4*)&nb[k][d];
        sacc += tv.x*nv.x + tv.y*nv.y + tv.z*nv.z + tv.w*nv.w;
    }
    float sc = sacc * 0.0625f;
    sc = (sc >= 0.0f) ? sc : 0.2f * sc;
    float m = sc;
    m = fmaxf(m, __shfl_xor(m, 8));
    m = fmaxf(m, __shfl_xor(m, 16));
    m = fmaxf(m, __shfl_xor(m, 32));
    float e = expf(sc - m);
    float den = e;
    den += __shfl_xor(den, 8); den += __shfl_xor(den, 16); den += __shfl_xor(den, 32);
    float w = e / den;

    int njk = nbr[i*KNN + k];
    const float* vp = &vproj[(size_t)(b*Jj + njk)*24 + h*3];
    float t0 = w * vp[0], t1 = w * vp[1], t2 = w * vp[2];
    #pragma unroll
    for (int u = 0; u < 4; ++u) {
        int e4 = l*4 + u;
        float hv = hi[e4];
        float4 wv = *(const float4*)&wsum[e4*4];
        t0 += hv * wv.x; t1 += hv * wv.y; t2 += hv * wv.z;
    }
    #pragma unroll
    for (int sft = 1; sft < 64; sft <<= 1) {
        t0 += __shfl_xor(t0, sft); t1 += __shfl_xor(t1, sft); t2 += __shfl_xor(t2, sft);
    }
    if (l == 0) {
        crd[i*4+0] = fmaxf(t0, 0.0f);
        crd[i*4+1] = fmaxf(t1, 0.0f);
        crd[i*4+2] = fmaxf(t2, 0.0f);
        crd[i*4+3] = 0.0f;
    }
}

// ---------------------------------------------------------------------------
// 16-bit MFMA GEMM (bf16 or f16), B^T input ([N][K]), segmented A along K,
// fp32 accum. 256 threads = 4 waves in 2x2; per-wave tile (BM/2)x(BN/2).
template<int BM, int BN, int BK, int NSEG, bool RELU_STATS, bool OUT_BF16, bool F16 = false>
__global__ __launch_bounds__(256)
void gemm_bt_kernel(const unsigned short* __restrict__ A0, int lda0, int klen0,
                    const unsigned short* __restrict__ A1, int lda1, int klen1,
                    const unsigned short* __restrict__ A2, int lda2, int klen2,
                    const unsigned short* __restrict__ Bt, int ldb,
                    void* __restrict__ Cv, int ldc, float* __restrict__ stat) {
    constexpr int WM = BM/2, WN = BN/2;
    constexpr int MW = WM/16, NW = WN/16, KW = BK/32;
    constexpr int CHUNKA = BM*BK/8;
    constexpr int CHUNKB = BN*BK/8;
    constexpr int KB8 = BK/8;
    using frag = std::conditional_t<F16, half8, short8>;
    __shared__ unsigned short As[BM*BK];
    __shared__ unsigned short Bs[BN*BK];
    __shared__ float red[4];

    int tid = threadIdx.x;
    int wid = tid >> 6, lane = tid & 63;
    int wr = wid >> 1, wc = wid & 1;
    int bm = blockIdx.x * BM, bn = blockIdx.y * BN;

    f32x4 acc[MW][NW];
    #pragma unroll
    for (int m = 0; m < MW; ++m)
        #pragma unroll
        for (int n = 0; n < NW; ++n)
            acc[m][n] = (f32x4){0.f, 0.f, 0.f, 0.f};

    const unsigned short* Aseg[3] = {A0, A1, A2};
    const int ldas[3] = {lda0, lda1, lda2};
    const int klens[3] = {klen0, klen1, klen2};

    int kglob = 0;
    for (int seg = 0; seg < NSEG; ++seg) {
        const unsigned short* A = Aseg[seg];
        const int lda = ldas[seg];
        const int klen = klens[seg];
        for (int k0 = 0; k0 < klen; k0 += BK) {
            #pragma unroll
            for (int it = 0; it < CHUNKA/256; ++it) {
                int c = tid + it*256;
                int row = c / KB8, kp = c % KB8;
                __builtin_amdgcn_global_load_lds(
                    (const __attribute__((address_space(1))) unsigned int*)
                        (A + (size_t)(bm + row)*lda + k0 + kp*8),
                    (__attribute__((address_space(3))) unsigned int*)(As + c*8),
                    16, 0, 0);
            }
            #pragma unroll
            for (int it = 0; it < CHUNKB/256; ++it) {
                int c = tid + it*256;
                int row = c / KB8, kp = c % KB8;
                __builtin_amdgcn_global_load_lds(
                    (const __attribute__((address_space(1))) unsigned int*)
                        (Bt + (size_t)(bn + row)*ldb + kglob + k0 + kp*8),
                    (__attribute__((address_space(3))) unsigned int*)(Bs + c*8),
                    16, 0, 0);
            }
            __syncthreads();
            #pragma unroll
            for (int kp = 0; kp < KW; ++kp) {
                frag af[MW], bf[NW];
                #pragma unroll
                for (int m = 0; m < MW; ++m)
                    af[m] = *(const frag*)&As[(wr*WM + m*16 + (lane & 15))*BK
                                             + kp*32 + (lane >> 4)*8];
                #pragma unroll
                for (int n = 0; n < NW; ++n)
                    bf[n] = *(const frag*)&Bs[(wc*WN + n*16 + (lane & 15))*BK
                                             + kp*32 + (lane >> 4)*8];
                #pragma unroll
                for (int m = 0; m < MW; ++m)
                    #pragma unroll
                    for (int n = 0; n < NW; ++n) {
                        if constexpr (F16)
                            acc[m][n] = __builtin_amdgcn_mfma_f32_16x16x32_f16(
                                af[m], bf[n], acc[m][n], 0, 0, 0);
                        else
                            acc[m][n] = __builtin_amdgcn_mfma_f32_16x16x32_bf16(
                                af[m], bf[n], acc[m][n], 0, 0, 0);
                    }
            }
            __syncthreads();
        }
        kglob += klen;
    }

    int cr = (lane >> 4)*4, cc = lane & 15;
    float bsum = 0.0f;
    #pragma unroll
    for (int m = 0; m < MW; ++m)
        #pragma unroll
        for (int n = 0; n < NW; ++n)
            #pragma unroll
            for (int j = 0; j < 4; ++j) {
                float v = acc[m][n][j];
                if (RELU_STATS) { v = fmaxf(v, 0.0f); bsum += v; }
                size_t row = bm + wr*WM + m*16 + cr + j;
                size_t col = bn + wc*WN + n*16 + cc;
                if (OUT_BF16) ((unsigned short*)Cv)[row*ldc + col] = f2bf(v);
                else          ((float*)Cv)[row*ldc + col] = v;
            }
    if (RELU_STATS) {
        #pragma unroll
        for (int sft = 1; sft < 64; sft <<= 1) bsum += __shfl_xor(bsum, sft);
        if (lane == 0) red[wid] = bsum;
        __syncthreads();
        if (tid == 0) atomicAdd(stat, red[0] + red[1] + red[2] + red[3]);
    }
}

// ---------------------------------------------------------------------------
// attention: one wave per (row, head-pair); 32 lanes per head, ushort8 loads.
__global__ __launch_bounds__(64)
void attn_kernel(const unsigned short* __restrict__ QKV,
                 const int* __restrict__ nbr, unsigned short* __restrict__ att) {
    int gid = blockIdx.x;
    int hp = gid & 3, row = gid >> 2, b = row / Jj;
    int lane = threadIdx.x;
    int h = hp*2 + (lane >> 5);
    int d0 = (lane & 31) * 8;

    u16x8 qu = *(const u16x8*)&QKV[(size_t)row*QKVN + h*Dd + d0];
    float qf[8];
    #pragma unroll
    for (int i = 0; i < 8; ++i) qf[i] = bf2f(qu[i]);
    const int* np_ = nbr + row * KNN;

    float sc[KNN]; int nb[KNN];
    #pragma unroll
    for (int k = 0; k < KNN; ++k) {
        int n = np_[k]; nb[k] = n;
        u16x8 ku = *(const u16x8*)&QKV[(size_t)(b*Jj + n)*QKVN + HD + h*Dd + d0];
        float p = 0;
        #pragma unroll
        for (int i = 0; i < 8; ++i) p += qf[i] * bf2f(ku[i]);
        #pragma unroll
        for (int s = 1; s < 32; s <<= 1) p += __shfl_xor(p, s);
        sc[k] = p;
    }
    float mx = -INFINITY;
    #pragma unroll
    for (int k = 0; k < KNN; ++k) {
        float s = sc[k] * 0.0625f;
        s = (s >= 0.0f) ? s : 0.2f * s;
        sc[k] = s; mx = fmaxf(mx, s);
    }
    float den = 0.0f;
    #pragma unroll
    for (int k = 0; k < KNN; ++k) { sc[k] = expf(sc[k] - mx); den += sc[k]; }
    float inv = 1.0f / den;
    float o[8] = {};
    #pragma unroll
    for (int k = 0; k < KNN; ++k) {
        u16x8 vu = *(const u16x8*)&QKV[(size_t)(b*Jj + nb[k])*QKVN + 2*HD + h*Dd + d0];
        float w = sc[k] * inv;
        #pragma unroll
        for (int i = 0; i < 8; ++i) o[i] += w * bf2f(vu[i]);
    }
    u16x8 ou;
    #pragma unroll
    for (int i = 0; i < 8; ++i) ou[i] = f2bf(o[i]);
    *(u16x8*)&att[(size_t)row*HD + h*Dd + d0] = ou;
}

// ---------------------------------------------------------------------------
__global__ __launch_bounds__(64)
void final_kernel(const float* __restrict__ h, const float* __restrict__ fcw,
                  const float* __restrict__ fcb, const float* __restrict__ stats,
                  float* __restrict__ out) {
    int row = blockIdx.x, lane = threadIdx.x;
    const float4 hv = *(const float4*)(h + (size_t)row*Cc + lane*4);
    float a0=0, a1=0, a2=0;
    const float hx[4] = {hv.x, hv.y, hv.z, hv.w};
    #pragma unroll
    for (int i = 0; i < 4; ++i) {
        int c = lane*4 + i;
        a0 += hx[i]*fcw[c*3+0]; a1 += hx[i]*fcw[c*3+1]; a2 += hx[i]*fcw[c*3+2];
    }
    #pragma unroll
    for (int s = 32; s > 0; s >>= 1) {
        a0 += __shfl_xor(a0, s); a1 += __shfl_xor(a1, s); a2 += __shfl_xor(a2, s);
    }
    if (lane == 0) {
        out[row*3+0] = a0 + fcb[0];
        out[row*3+1] = a1 + fcb[1];
        out[row*3+2] = a2 + fcb[2];
        if (row == 0)
            out[(size_t)Mrows*3] =
                (stats[0] + stats[1]) * (0.5f / ((float)Mrows * (float)Cc));
    }
}

// ---------------------------------------------------------------------------
extern "C" void kernel_launch(void* const* d_in, const int* in_sizes, int n_in,
                              void* d_out, int out_size, void* d_ws, size_t ws_size,
                              hipStream_t stream) {
    (void)in_sizes; (void)n_in; (void)out_size; (void)ws_size;
    const float* jf     = (const float*)d_in[0];
    const float* wq     = (const float*)d_in[1];
    const float* wk     = (const float*)d_in[2];
    const float* wv     = (const float*)d_in[3];
    const float* wp     = (const float*)d_in[4];
    const float* wsw    = (const float*)d_in[5];
    const float* wskip0 = (const float*)d_in[6];
    const float* fcw    = (const float*)d_in[7];
    const float* fcb    = (const float*)d_in[8];
    float* out = (float*)d_out;

    char* wsb = (char*)d_ws;
    unsigned short* QKVb  = (unsigned short*)(wsb + OFF_QKV);
    float*          Tm    = (float*)(wsb + OFF_T);          // aliases QKV region
    unsigned short* attb  = (unsigned short*)(wsb + OFF_ATT);
    _Float16*       GT    = (_Float16*)(wsb + OFF_GT);
    unsigned short* jfb   = (unsigned short*)(wsb + OFF_JFB);
    _Float16*       jfh   = (_Float16*)(wsb + OFF_JFH);
    _Float16*       jfl   = (_Float16*)(wsb + OFF_JFL);
    _Float16*       jfd   = (_Float16*)(wsb + OFF_JFD);
    unsigned short* h1b   = (unsigned short*)(wsb + OFF_H1B);
    float*          h2f   = (float*)(wsb + OFF_H2F);
    unsigned short* wqkvT = (unsigned short*)(wsb + OFF_WQKVT);
    unsigned short* fbt   = (unsigned short*)(wsb + OFF_FBT);
    float*          Wvp   = (float*)(wsb + OFF_WVP);
    float*          vproj = (float*)(wsb + OFF_VPROJ);
    float*          wsum  = (float*)(wsb + OFF_WSUM);
    float*          crd   = (float*)(wsb + OFF_CRD);
    int*            nbr0  = (int*)(wsb + OFF_NBR0);
    int*            nbr1  = (int*)(wsb + OFF_NBR1);
    float*          stats = (float*)(wsb + OFF_STAT);

    // ---- prep ----
    prep_weights_kernel<<<4353, 256, 0, stream>>>(wq, wk, wv, wp, wsw, wskip0,
                                                  wqkvT, fbt, stats, wsum);
    cvt_split_kernel<<<(Mrows*Cc/4 + 255)/256, 256, 0, stream>>>(
        jf, jfb, jfh, jfl, jfd, Mrows*Cc/4);
    g_gemm_kernel<<<dim3(4, 4, 8), 256, 0, stream>>>(wq, wk, GT);
    // T = jfh@Gh + (16*jfl)@(G/16) + (jf/128)@(128*Gl)   [fp16 MFMA, fp32 out]
    gemm_bt_kernel<128,128,64,3,false,false,true><<<dim3(Mrows/128, HD/128), 256, 0, stream>>>(
        (const unsigned short*)jfh, Cc, Cc, (const unsigned short*)jfl, Cc, Cc,
        (const unsigned short*)jfd, Cc, Cc, (const unsigned short*)GT, 768,
        Tm, HD, nullptr);
    wvp_kernel<<<8, 256, 0, stream>>>(wv, wp, Wvp);
    vproj_kernel<<<Mrows/8, 256, 0, stream>>>(jf, Wvp, vproj);

    // ---- layer 0 ----
    knn_kernel<<<Bb, 64, 0, stream>>>(jf, Cc, nbr0);
    precise_kernel<<<Mrows, 64, 0, stream>>>(Tm, jf, nbr0, vproj, wsum, crd);
    gemm_bt_kernel<128,128,64,1,false,true><<<dim3(Mrows/128, QKVN/128), 256, 0, stream>>>(
        jfb, Cc, Cc, jfb, Cc, 0, jfb, Cc, 0, wqkvT, Cc, QKVb, QKVN, nullptr);
    attn_kernel<<<Mrows*4, 64, 0, stream>>>(QKVb, nbr0, attb);
    gemm_bt_kernel<64,64,64,3,true,true><<<dim3(Mrows/64, Cc/64), 256, 0, stream>>>(
        attb, HD, HD, jfb, Cc, Cc, jfb, Cc, Cc, fbt, KFUSE, h1b, Cc, &stats[0]);

    // ---- layer 1 ----
    knn_kernel<<<Bb, 64, 0, stream>>>(crd, 4, nbr1);
    gemm_bt_kernel<128,128,64,1,false,true><<<dim3(Mrows/128, QKVN/128), 256, 0, stream>>>(
        h1b, Cc, Cc, h1b, Cc, 0, h1b, Cc, 0, wqkvT + (size_t)QKVN*Cc, Cc, QKVb, QKVN, nullptr);
    attn_kernel<<<Mrows*4, 64, 0, stream>>>(QKVb, nbr1, attb);
    gemm_bt_kernel<64,64,64,3,true,false><<<dim3(Mrows/64, Cc/64), 256, 0, stream>>>(
        attb, HD, HD, h1b, Cc, Cc, jfb, Cc, Cc, fbt + (size_t)Cc*KFUSE, KFUSE, h2f, Cc, &stats[1]);

    // ---- final ----
    final_kernel<<<Mrows, 64, 0, stream>>>(h2f, fcw, fcb, stats, out);
}

// Round 8
// 278.754 us; speedup vs baseline: 1.6149x; 1.1251x over previous
//
#include <hip/hip_runtime.h>
#include <hip/hip_bf16.h>
#include <math.h>
#include <type_traits>

namespace {
constexpr int Bb = 256, Jj = 21, Cc = 256, Hh = 8, Dd = 256;
constexpr int Mrows = Bb * Jj;      // 5376
constexpr int HD    = Hh * Dd;      // 2048
constexpr int QKVN  = 3 * HD;       // 6144
constexpr int KNN   = 8;
constexpr int KFUSE = HD + Cc + Cc; // 2560

// ---- workspace byte offsets ----
constexpr size_t OFF_QKV   = 0;                                   // bf16 5376x6144
constexpr size_t OFF_T     = 0;                                   // f32  5376x2048 (alias, dead before QKV write)
constexpr size_t OFF_ATT   = OFF_QKV   + (size_t)Mrows*QKVN*2;    // bf16 5376x2048
constexpr size_t OFF_GT    = OFF_ATT   + (size_t)Mrows*HD*2;      // f16  2048x768
constexpr size_t OFF_JFB   = OFF_GT    + (size_t)HD*768*2;        // bf16 5376x256
constexpr size_t OFF_JFH   = OFF_JFB   + (size_t)Mrows*Cc*2;      // f16  5376x256
constexpr size_t OFF_JFL   = OFF_JFH   + (size_t)Mrows*Cc*2;      // f16  5376x256
constexpr size_t OFF_JFD   = OFF_JFL   + (size_t)Mrows*Cc*2;      // f16  5376x256
constexpr size_t OFF_H1B   = OFF_JFD   + (size_t)Mrows*Cc*2;      // bf16 5376x256
constexpr size_t OFF_H2F   = OFF_H1B   + (size_t)Mrows*Cc*2;      // f32  5376x256
constexpr size_t OFF_WQKVT = OFF_H2F   + (size_t)Mrows*Cc*4;      // bf16 2x6144x256
constexpr size_t OFF_FBT   = OFF_WQKVT + (size_t)2*QKVN*Cc*2;     // bf16 2x256x2560
constexpr size_t OFF_WVP   = OFF_FBT   + (size_t)2*Cc*KFUSE*2;    // f32  256x24
constexpr size_t OFF_VPROJ = OFF_WVP   + (size_t)Cc*24*4;         // f32  5376x24
constexpr size_t OFF_WSUM  = OFF_VPROJ + (size_t)Mrows*24*4;      // f32  256x4
constexpr size_t OFF_CRD   = OFF_WSUM  + (size_t)Cc*4*4;          // f32  5376x4
constexpr size_t OFF_NBR0  = OFF_CRD   + (size_t)Mrows*4*4;       // int  5376x8
constexpr size_t OFF_NBR1  = OFF_NBR0  + (size_t)Mrows*KNN*4;
constexpr size_t OFF_STAT  = OFF_NBR1  + (size_t)Mrows*KNN*4;     // 2 f32
} // namespace

typedef short short8 __attribute__((ext_vector_type(8)));
typedef _Float16 half8 __attribute__((ext_vector_type(8)));
typedef _Float16 half4v __attribute__((ext_vector_type(4)));
typedef unsigned short u16x8 __attribute__((ext_vector_type(8)));
typedef float f32x4 __attribute__((ext_vector_type(4)));

__device__ __forceinline__ unsigned short f2bf(float x) {
    unsigned int u = __float_as_uint(x);
    u = u + 0x7fffu + ((u >> 16) & 1u);            // round-to-nearest-even
    return (unsigned short)(u >> 16);
}
__device__ __forceinline__ float bf2f(unsigned short b) {
    return __uint_as_float(((unsigned int)b) << 16);
}

// ---------------------------------------------------------------------------
// exact stable-argsort kNN: ranks 1..8 by (d2, index) ascending
__global__ __launch_bounds__(64)
void knn_kernel(const float* __restrict__ src, int ld, int* __restrict__ nbr) {
    int b = blockIdx.x;
    __shared__ float cs[Jj][3];
    int t = threadIdx.x;
    if (t < Jj) {
        const float* p = src + (size_t)(b * Jj + t) * ld;
        cs[t][0] = p[0]; cs[t][1] = p[1]; cs[t][2] = p[2];
    }
    __syncthreads();
    if (t < Jj) {
        float x = cs[t][0], y = cs[t][1], z = cs[t][2];
        float d2[Jj];
        #pragma unroll
        for (int jj = 0; jj < Jj; ++jj) {
            float dx = x - cs[jj][0], dy = y - cs[jj][1], dz = z - cs[jj][2];
            d2[jj] = dx*dx + dy*dy + dz*dz;
        }
        unsigned int used = 0u;
        int out_base = (b * Jj + t) * KNN;
        #pragma unroll
        for (int r = 0; r <= KNN; ++r) {
            int best = -1; float bd = INFINITY;
            #pragma unroll
            for (int jj = 0; jj < Jj; ++jj)
                if (!((used >> jj) & 1u) && d2[jj] < bd) { bd = d2[jj]; best = jj; }
            used |= (1u << best);
            if (r > 0) nbr[out_base + r - 1] = best;
        }
    }
}

// ---------------------------------------------------------------------------
// fp32 -> bf16 + fp16 3-way split (hi, 16*lo, x/128), vectorized x4
__global__ __launch_bounds__(256)
void cvt_split_kernel(const float* __restrict__ in, unsigned short* __restrict__ outB,
                      _Float16* __restrict__ outH, _Float16* __restrict__ outL,
                      _Float16* __restrict__ outD, int n4) {
    int i = blockIdx.x * 256 + threadIdx.x;
    if (i < n4) {
        float4 v = ((const float4*)in)[i];
        float x[4] = {v.x, v.y, v.z, v.w};
        ushort4 ob; half4v oh, ol, od;
        #pragma unroll
        for (int u = 0; u < 4; ++u) {
            ((unsigned short*)&ob)[u] = f2bf(x[u]);
            _Float16 h = (_Float16)x[u];
            oh[u] = h;
            ol[u] = (_Float16)((x[u] - (float)h) * 16.0f);
            od[u] = (_Float16)(x[u] * 0.0078125f);   // /128
        }
        ((ushort4*)outB)[i] = ob;
        ((half4v*)outH)[i] = oh;
        ((half4v*)outL)[i] = ol;
        ((half4v*)outD)[i] = od;
    }
}

// ---------------------------------------------------------------------------
// All 12 weight transposes (fp32 [K][N] -> bf16 [N][K]) + stats zero + wsum.
__global__ __launch_bounds__(256)
void prep_weights_kernel(const float* __restrict__ wq, const float* __restrict__ wk,
                         const float* __restrict__ wv, const float* __restrict__ wp,
                         const float* __restrict__ wsw, const float* __restrict__ wsk,
                         unsigned short* __restrict__ wqkvT,
                         unsigned short* __restrict__ fbt, float* __restrict__ stats,
                         float* __restrict__ wsum) {
    int bid = blockIdx.x;
    if (bid == 4352) {       // wsum[e][c] = ws0[e][c] + wskip0[e][c], c<3
        int e = threadIdx.x;
        float4 o;
        o.x = wsw[(size_t)e*Dd + 0] + wsk[(size_t)e*Dd + 0];
        o.y = wsw[(size_t)e*Dd + 1] + wsk[(size_t)e*Dd + 1];
        o.z = wsw[(size_t)e*Dd + 2] + wsk[(size_t)e*Dd + 2];
        o.w = 0.0f;
        *(float4*)&wsum[e*4] = o;
        if (e < 2) stats[e] = 0.0f;
        return;
    }
    const float* src; unsigned short* dst;
    int ldin, ldout, tilesX, tile;
    constexpr size_t CH = (size_t)Cc * HD;
    if (bid < 3072) {
        int op = bid >> 9; tile = bid & 511; tilesX = 64;
        ldin = HD; ldout = Cc;
        const float* s3[3] = {wq, wk, wv};
        src = s3[op % 3] + (size_t)(op / 3) * CH;
        dst = wqkvT + (size_t)(op % 3) * HD * Cc + (size_t)(op / 3) * QKVN * Cc;
    } else if (bid < 4096) {
        int op = (bid - 3072) >> 9; tile = (bid - 3072) & 511; tilesX = 8;
        ldin = Cc; ldout = KFUSE;
        src = wp + (size_t)op * HD * Cc;
        dst = fbt + (size_t)op * Cc * KFUSE;
    } else {
        int q = bid - 4096; int op = q >> 6; tile = q & 63; tilesX = 8;
        ldin = Cc; ldout = KFUSE;
        const float* s4[4] = {wsw, wsw + (size_t)Cc * Cc, wsk, wsk};
        src = s4[op];
        dst = fbt + (size_t)(op & 1) * Cc * KFUSE + HD + (size_t)(op >> 1) * Cc;
    }
    int bx = tile % tilesX, by = tile / tilesX;
    int n0 = bx * 32, k0 = by * 32;

    __shared__ float t[32][33];
    int r = threadIdx.x >> 3, c4 = (threadIdx.x & 7) * 4;
    float4 v = *(const float4*)&src[(size_t)(k0 + r) * ldin + n0 + c4];
    t[r][c4+0] = v.x; t[r][c4+1] = v.y; t[r][c4+2] = v.z; t[r][c4+3] = v.w;
    __syncthreads();
    ushort4 o;
    o.x = f2bf(t[c4+0][r]); o.y = f2bf(t[c4+1][r]);
    o.z = f2bf(t[c4+2][r]); o.w = f2bf(t[c4+3][r]);
    *(ushort4*)&dst[(size_t)(n0 + r) * ldout + k0 + c4] = o;
}

// ---------------------------------------------------------------------------
// G_h = wq_h @ wk_h^T (fp32 accum), emitted as fp16-split B^T panels.
__global__ __launch_bounds__(256)
void g_gemm_kernel(const float* __restrict__ wq, const float* __restrict__ wk,
                   _Float16* __restrict__ GT) {
    constexpr int LDR = 68;
    __shared__ float As[32][LDR];
    __shared__ float Ws[32][LDR];
    int h = blockIdx.z;
    int m0 = blockIdx.x * 64, n0 = blockIdx.y * 64;
    int tid = threadIdx.x;
    int ty = tid >> 4, tx = tid & 15;
    float acc[4][4] = {};
    for (int kb = 0; kb < 256; kb += 32) {
        #pragma unroll
        for (int it = 0; it < 2; ++it) {
            int c = tid + it * 256;
            int row = c >> 3, col = (c & 7) * 4;
            float4 v = *(const float4*)&wq[(size_t)(m0 + row)*HD + h*256 + kb + col];
            float4 u = *(const float4*)&wk[(size_t)(n0 + row)*HD + h*256 + kb + col];
            As[col+0][row] = v.x; As[col+1][row] = v.y;
            As[col+2][row] = v.z; As[col+3][row] = v.w;
            Ws[col+0][row] = u.x; Ws[col+1][row] = u.y;
            Ws[col+2][row] = u.z; Ws[col+3][row] = u.w;
        }
        __syncthreads();
        #pragma unroll
        for (int kk = 0; kk < 32; ++kk) {
            float4 a = *(const float4*)&As[kk][ty*4];
            float4 b = *(const float4*)&Ws[kk][tx*4];
            float av[4] = {a.x, a.y, a.z, a.w};
            float bv[4] = {b.x, b.y, b.z, b.w};
            #pragma unroll
            for (int i = 0; i < 4; ++i)
                #pragma unroll
                for (int j = 0; j < 4; ++j)
                    acc[i][j] += av[i] * bv[j];
        }
        __syncthreads();
    }
    #pragma unroll
    for (int j = 0; j < 4; ++j) {
        int n = h*256 + n0 + tx*4 + j;
        half4v hi, hs, lo;
        #pragma unroll
        for (int i = 0; i < 4; ++i) {
            float g = acc[i][j];
            _Float16 gh = (_Float16)g;
            hi[i] = gh;
            hs[i] = (_Float16)(g * 0.0625f);
            lo[i] = (_Float16)((g - (float)gh) * 128.0f);
        }
        _Float16* base = &GT[(size_t)n*768 + m0 + ty*4];
        *(half4v*)(base)       = hi;
        *(half4v*)(base + 256) = hs;
        *(half4v*)(base + 512) = lo;
    }
}

// ---------------------------------------------------------------------------
// Wvp2[e][h*3+c] = sum_d wv[e][h*256+d] * wp[h*256+d][c].  grid (8), 256 thr
__global__ __launch_bounds__(256)
void wvp_kernel(const float* __restrict__ wv, const float* __restrict__ wp,
                float* __restrict__ Wvp2) {
    int h = blockIdx.x;
    __shared__ float wpc[256][3];
    int t = threadIdx.x;
    const float* p = &wp[(size_t)(h*256 + t) * Cc];
    wpc[t][0] = p[0]; wpc[t][1] = p[1]; wpc[t][2] = p[2];
    __syncthreads();
    const float* vr = &wv[(size_t)t*HD + h*256];
    float a0=0, a1=0, a2=0;
    for (int d = 0; d < 256; ++d) {
        float v = vr[d];
        a0 += v*wpc[d][0]; a1 += v*wpc[d][1]; a2 += v*wpc[d][2];
    }
    float* o = &Wvp2[(size_t)t*24 + h*3];
    o[0]=a0; o[1]=a1; o[2]=a2;
}

// ---------------------------------------------------------------------------
// vproj[j][o] = sum_e h0[j][e] * Wvp2[e][o], o<24.  8 rows/block, 256 thr.
__global__ __launch_bounds__(256)
void vproj_kernel(const float* __restrict__ h0, const float* __restrict__ Wvp2,
                  float* __restrict__ vproj) {
    __shared__ float hr[8][256];
    __shared__ float wl[6144];
    int t = threadIdx.x;
    int j0 = blockIdx.x * 8;
    #pragma unroll
    for (int i = 0; i < 6; ++i)
        *(float4*)&wl[t*4 + i*1024] = *(const float4*)&Wvp2[t*4 + i*1024];
    {
        int r = t >> 5, c = (t & 31) * 8;
        const float* src = &h0[(size_t)(j0 + r)*Cc + c];
        *(float4*)&hr[r][c]   = *(const float4*)src;
        *(float4*)&hr[r][c+4] = *(const float4*)(src + 4);
    }
    __syncthreads();
    int r = t >> 5, o = t & 31;
    if (o < 24) {
        float a = 0.0f;
        for (int e = 0; e < 256; ++e) a += hr[r][e] * wl[e*24 + o];
        vproj[(size_t)(j0 + r)*24 + o] = a;
    }
}

// ---------------------------------------------------------------------------
// precise layer-0 coords
__global__ __launch_bounds__(64)
void precise_kernel(const float* __restrict__ T, const float* __restrict__ h0,
                    const int* __restrict__ nbr, const float* __restrict__ vproj,
                    const float* __restrict__ wsum, float* __restrict__ crd) {
    int i = blockIdx.x;
    int b = i / Jj;
    int l = threadIdx.x;
    __shared__ float Ts[8][260];
    __shared__ float nb[8][260];
    __shared__ float hi[256];
    #pragma unroll
    for (int u = 0; u < 8; ++u) {
        int idx = u*64 + l;
        float4 v = *(const float4*)&T[(size_t)i*HD + idx*4];
        int hh = idx >> 6, dd = (idx & 63) * 4;
        *(float4*)&Ts[hh][dd] = v;
    }
    *(float4*)&hi[l*4] = *(const float4*)&h0[(size_t)i*Cc + l*4];
    int kq = l >> 3, s = l & 7;
    int njs = nbr[i*KNN + kq];
    const float* nrow = &h0[(size_t)(b*Jj + njs)*Cc];
    #pragma unroll
    for (int u = 0; u < 8; ++u)
        *(float4*)&nb[kq][(s*8+u)*4] = *(const float4*)&nrow[(s*8+u)*4];
    __syncthreads();

    int k = l >> 3, h = l & 7;
    float sacc = 0;
    #pragma unroll 8
    for (int d = 0; d < 256; d += 4) {
        float4 tv = *(const float4*)&Ts[h][d];
        float4 nv = *(const float4*)&nb[k][d];
        sacc += tv.x*nv.x + tv.y*nv.y + tv.z*nv.z + tv.w*nv.w;
    }
    float sc = sacc * 0.0625f;
    sc = (sc >= 0.0f) ? sc : 0.2f * sc;
    float m = sc;
    m = fmaxf(m, __shfl_xor(m, 8));
    m = fmaxf(m, __shfl_xor(m, 16));
    m = fmaxf(m, __shfl_xor(m, 32));
    float e = expf(sc - m);
    float den = e;
    den += __shfl_xor(den, 8); den += __shfl_xor(den, 16); den += __shfl_xor(den, 32);
    float w = e / den;

    int njk = nbr[i*KNN + k];
    const float* vp = &vproj[(size_t)(b*Jj + njk)*24 + h*3];
    float t0 = w * vp[0], t1 = w * vp[1], t2 = w * vp[2];
    #pragma unroll
    for (int u = 0; u < 4; ++u) {
        int e4 = l*4 + u;
        float hv = hi[e4];
        float4 wv = *(const float4*)&wsum[e4*4];
        t0 += hv * wv.x; t1 += hv * wv.y; t2 += hv * wv.z;
    }
    #pragma unroll
    for (int sft = 1; sft < 64; sft <<= 1) {
        t0 += __shfl_xor(t0, sft); t1 += __shfl_xor(t1, sft); t2 += __shfl_xor(t2, sft);
    }
    if (l == 0) {
        crd[i*4+0] = fmaxf(t0, 0.0f);
        crd[i*4+1] = fmaxf(t1, 0.0f);
        crd[i*4+2] = fmaxf(t2, 0.0f);
        crd[i*4+3] = 0.0f;
    }
}

// ---------------------------------------------------------------------------
// 16-bit MFMA GEMM (bf16 or f16), B^T input ([N][K]), segmented A along K,
// fp32 accum. XOR-swizzled LDS (T2, rule #21): global SOURCE column is
// inverse-permuted, LDS dest stays linear (global_load_lds requirement),
// fragment reads apply the same XOR -> 16-lane column reads spread over all
// 8 16B-slots (2-way aliasing = free) instead of 16-way same-bank conflict.
template<int BM, int BN, int BK, int NSEG, bool RELU_STATS, bool OUT_BF16, bool F16 = false>
__global__ __launch_bounds__(256)
void gemm_bt_kernel(const unsigned short* __restrict__ A0, int lda0, int klen0,
                    const unsigned short* __restrict__ A1, int lda1, int klen1,
                    const unsigned short* __restrict__ A2, int lda2, int klen2,
                    const unsigned short* __restrict__ Bt, int ldb,
                    void* __restrict__ Cv, int ldc, float* __restrict__ stat) {
    constexpr int WM = BM/2, WN = BN/2;
    constexpr int MW = WM/16, NW = WN/16, KW = BK/32;
    constexpr int CHUNKA = BM*BK/8;
    constexpr int CHUNKB = BN*BK/8;
    constexpr int KB8 = BK/8;          // 16B chunks per LDS row
    constexpr int SWZ = KB8 - 1;       // XOR mask
    using frag = std::conditional_t<F16, half8, short8>;
    __shared__ unsigned short As[BM*BK];
    __shared__ unsigned short Bs[BN*BK];
    __shared__ float red[4];

    int tid = threadIdx.x;
    int wid = tid >> 6, lane = tid & 63;
    int wr = wid >> 1, wc = wid & 1;
    int bm = blockIdx.x * BM, bn = blockIdx.y * BN;

    f32x4 acc[MW][NW];
    #pragma unroll
    for (int m = 0; m < MW; ++m)
        #pragma unroll
        for (int n = 0; n < NW; ++n)
            acc[m][n] = (f32x4){0.f, 0.f, 0.f, 0.f};

    const unsigned short* Aseg[3] = {A0, A1, A2};
    const int ldas[3] = {lda0, lda1, lda2};
    const int klens[3] = {klen0, klen1, klen2};

    int kglob = 0;
    for (int seg = 0; seg < NSEG; ++seg) {
        const unsigned short* A = Aseg[seg];
        const int lda = ldas[seg];
        const int klen = klens[seg];
        for (int k0 = 0; k0 < klen; k0 += BK) {
            #pragma unroll
            for (int it = 0; it < CHUNKA/256; ++it) {
                int c = tid + it*256;
                int row = c / KB8;
                int kp = (c % KB8) ^ (row & SWZ);   // inverse-permuted source
                __builtin_amdgcn_global_load_lds(
                    (const __attribute__((address_space(1))) unsigned int*)
                        (A + (size_t)(bm + row)*lda + k0 + kp*8),
                    (__attribute__((address_space(3))) unsigned int*)(As + c*8),
                    16, 0, 0);
            }
            #pragma unroll
            for (int it = 0; it < CHUNKB/256; ++it) {
                int c = tid + it*256;
                int row = c / KB8;
                int kp = (c % KB8) ^ (row & SWZ);
                __builtin_amdgcn_global_load_lds(
                    (const __attribute__((address_space(1))) unsigned int*)
                        (Bt + (size_t)(bn + row)*ldb + kglob + k0 + kp*8),
                    (__attribute__((address_space(3))) unsigned int*)(Bs + c*8),
                    16, 0, 0);
            }
            __syncthreads();
            #pragma unroll
            for (int kp = 0; kp < KW; ++kp) {
                frag af[MW], bf[NW];
                int cbase = kp*4 + (lane >> 4);     // chunk col 0..KB8-1
                #pragma unroll
                for (int m = 0; m < MW; ++m) {
                    int r = wr*WM + m*16 + (lane & 15);
                    af[m] = *(const frag*)&As[r*BK + ((cbase ^ (r & SWZ))*8)];
                }
                #pragma unroll
                for (int n = 0; n < NW; ++n) {
                    int r = wc*WN + n*16 + (lane & 15);
                    bf[n] = *(const frag*)&Bs[r*BK + ((cbase ^ (r & SWZ))*8)];
                }
                #pragma unroll
                for (int m = 0; m < MW; ++m)
                    #pragma unroll
                    for (int n = 0; n < NW; ++n) {
                        if constexpr (F16)
                            acc[m][n] = __builtin_amdgcn_mfma_f32_16x16x32_f16(
                                af[m], bf[n], acc[m][n], 0, 0, 0);
                        else
                            acc[m][n] = __builtin_amdgcn_mfma_f32_16x16x32_bf16(
                                af[m], bf[n], acc[m][n], 0, 0, 0);
                    }
            }
            __syncthreads();
        }
        kglob += klen;
    }

    int cr = (lane >> 4)*4, cc = lane & 15;
    float bsum = 0.0f;
    #pragma unroll
    for (int m = 0; m < MW; ++m)
        #pragma unroll
        for (int n = 0; n < NW; ++n)
            #pragma unroll
            for (int j = 0; j < 4; ++j) {
                float v = acc[m][n][j];
                if (RELU_STATS) { v = fmaxf(v, 0.0f); bsum += v; }
                size_t row = bm + wr*WM + m*16 + cr + j;
                size_t col = bn + wc*WN + n*16 + cc;
                if (OUT_BF16) ((unsigned short*)Cv)[row*ldc + col] = f2bf(v);
                else          ((float*)Cv)[row*ldc + col] = v;
            }
    if (RELU_STATS) {
        #pragma unroll
        for (int sft = 1; sft < 64; sft <<= 1) bsum += __shfl_xor(bsum, sft);
        if (lane == 0) red[wid] = bsum;
        __syncthreads();
        if (tid == 0) atomicAdd(stat, red[0] + red[1] + red[2] + red[3]);
    }
}

// ---------------------------------------------------------------------------
// attention: one wave per (row, head-pair); 32 lanes per head, ushort8 loads.
__global__ __launch_bounds__(64)
void attn_kernel(const unsigned short* __restrict__ QKV,
                 const int* __restrict__ nbr, unsigned short* __restrict__ att) {
    int gid = blockIdx.x;
    int hp = gid & 3, row = gid >> 2, b = row / Jj;
    int lane = threadIdx.x;
    int h = hp*2 + (lane >> 5);
    int d0 = (lane & 31) * 8;

    u16x8 qu = *(const u16x8*)&QKV[(size_t)row*QKVN + h*Dd + d0];
    float qf[8];
    #pragma unroll
    for (int i = 0; i < 8; ++i) qf[i] = bf2f(qu[i]);
    const int* np_ = nbr + row * KNN;

    float sc[KNN]; int nb[KNN];
    #pragma unroll
    for (int k = 0; k < KNN; ++k) {
        int n = np_[k]; nb[k] = n;
        u16x8 ku = *(const u16x8*)&QKV[(size_t)(b*Jj + n)*QKVN + HD + h*Dd + d0];
        float p = 0;
        #pragma unroll
        for (int i = 0; i < 8; ++i) p += qf[i] * bf2f(ku[i]);
        #pragma unroll
        for (int s = 1; s < 32; s <<= 1) p += __shfl_xor(p, s);
        sc[k] = p;
    }
    float mx = -INFINITY;
    #pragma unroll
    for (int k = 0; k < KNN; ++k) {
        float s = sc[k] * 0.0625f;
        s = (s >= 0.0f) ? s : 0.2f * s;
        sc[k] = s; mx = fmaxf(mx, s);
    }
    float den = 0.0f;
    #pragma unroll
    for (int k = 0; k < KNN; ++k) { sc[k] = expf(sc[k] - mx); den += sc[k]; }
    float inv = 1.0f / den;
    float o[8] = {};
    #pragma unroll
    for (int k = 0; k < KNN; ++k) {
        u16x8 vu = *(const u16x8*)&QKV[(size_t)(b*Jj + nb[k])*QKVN + 2*HD + h*Dd + d0];
        float w = sc[k] * inv;
        #pragma unroll
        for (int i = 0; i < 8; ++i) o[i] += w * bf2f(vu[i]);
    }
    u16x8 ou;
    #pragma unroll
    for (int i = 0; i < 8; ++i) ou[i] = f2bf(o[i]);
    *(u16x8*)&att[(size_t)row*HD + h*Dd + d0] = ou;
}

// ---------------------------------------------------------------------------
__global__ __launch_bounds__(64)
void final_kernel(const float* __restrict__ h, const float* __restrict__ fcw,
                  const float* __restrict__ fcb, const float* __restrict__ stats,
                  float* __restrict__ out) {
    int row = blockIdx.x, lane = threadIdx.x;
    const float4 hv = *(const float4*)(h + (size_t)row*Cc + lane*4);
    float a0=0, a1=0, a2=0;
    const float hx[4] = {hv.x, hv.y, hv.z, hv.w};
    #pragma unroll
    for (int i = 0; i < 4; ++i) {
        int c = lane*4 + i;
        a0 += hx[i]*fcw[c*3+0]; a1 += hx[i]*fcw[c*3+1]; a2 += hx[i]*fcw[c*3+2];
    }
    #pragma unroll
    for (int s = 32; s > 0; s >>= 1) {
        a0 += __shfl_xor(a0, s); a1 += __shfl_xor(a1, s); a2 += __shfl_xor(a2, s);
    }
    if (lane == 0) {
        out[row*3+0] = a0 + fcb[0];
        out[row*3+1] = a1 + fcb[1];
        out[row*3+2] = a2 + fcb[2];
        if (row == 0)
            out[(size_t)Mrows*3] =
                (stats[0] + stats[1]) * (0.5f / ((float)Mrows * (float)Cc));
    }
}

// ---------------------------------------------------------------------------
extern "C" void kernel_launch(void* const* d_in, const int* in_sizes, int n_in,
                              void* d_out, int out_size, void* d_ws, size_t ws_size,
                              hipStream_t stream) {
    (void)in_sizes; (void)n_in; (void)out_size; (void)ws_size;
    const float* jf     = (const float*)d_in[0];
    const float* wq     = (const float*)d_in[1];
    const float* wk     = (const float*)d_in[2];
    const float* wv     = (const float*)d_in[3];
    const float* wp     = (const float*)d_in[4];
    const float* wsw    = (const float*)d_in[5];
    const float* wskip0 = (const float*)d_in[6];
    const float* fcw    = (const float*)d_in[7];
    const float* fcb    = (const float*)d_in[8];
    float* out = (float*)d_out;

    char* wsb = (char*)d_ws;
    unsigned short* QKVb  = (unsigned short*)(wsb + OFF_QKV);
    float*          Tm    = (float*)(wsb + OFF_T);          // aliases QKV region
    unsigned short* attb  = (unsigned short*)(wsb + OFF_ATT);
    _Float16*       GT    = (_Float16*)(wsb + OFF_GT);
    unsigned short* jfb   = (unsigned short*)(wsb + OFF_JFB);
    _Float16*       jfh   = (_Float16*)(wsb + OFF_JFH);
    _Float16*       jfl   = (_Float16*)(wsb + OFF_JFL);
    _Float16*       jfd   = (_Float16*)(wsb + OFF_JFD);
    unsigned short* h1b   = (unsigned short*)(wsb + OFF_H1B);
    float*          h2f   = (float*)(wsb + OFF_H2F);
    unsigned short* wqkvT = (unsigned short*)(wsb + OFF_WQKVT);
    unsigned short* fbt   = (unsigned short*)(wsb + OFF_FBT);
    float*          Wvp   = (float*)(wsb + OFF_WVP);
    float*          vproj = (float*)(wsb + OFF_VPROJ);
    float*          wsum  = (float*)(wsb + OFF_WSUM);
    float*          crd   = (float*)(wsb + OFF_CRD);
    int*            nbr0  = (int*)(wsb + OFF_NBR0);
    int*            nbr1  = (int*)(wsb + OFF_NBR1);
    float*          stats = (float*)(wsb + OFF_STAT);

    // ---- prep ----
    prep_weights_kernel<<<4353, 256, 0, stream>>>(wq, wk, wv, wp, wsw, wskip0,
                                                  wqkvT, fbt, stats, wsum);
    cvt_split_kernel<<<(Mrows*Cc/4 + 255)/256, 256, 0, stream>>>(
        jf, jfb, jfh, jfl, jfd, Mrows*Cc/4);
    g_gemm_kernel<<<dim3(4, 4, 8), 256, 0, stream>>>(wq, wk, GT);
    // T = jfh@Gh + (16*jfl)@(G/16) + (jf/128)@(128*Gl)   [fp16 MFMA, fp32 out]
    gemm_bt_kernel<128,128,64,3,false,false,true><<<dim3(Mrows/128, HD/128), 256, 0, stream>>>(
        (const unsigned short*)jfh, Cc, Cc, (const unsigned short*)jfl, Cc, Cc,
        (const unsigned short*)jfd, Cc, Cc, (const unsigned short*)GT, 768,
        Tm, HD, nullptr);
    wvp_kernel<<<8, 256, 0, stream>>>(wv, wp, Wvp);
    vproj_kernel<<<Mrows/8, 256, 0, stream>>>(jf, Wvp, vproj);

    // ---- layer 0 ----
    knn_kernel<<<Bb, 64, 0, stream>>>(jf, Cc, nbr0);
    precise_kernel<<<Mrows, 64, 0, stream>>>(Tm, jf, nbr0, vproj, wsum, crd);
    gemm_bt_kernel<128,128,64,1,false,true><<<dim3(Mrows/128, QKVN/128), 256, 0, stream>>>(
        jfb, Cc, Cc, jfb, Cc, 0, jfb, Cc, 0, wqkvT, Cc, QKVb, QKVN, nullptr);
    attn_kernel<<<Mrows*4, 64, 0, stream>>>(QKVb, nbr0, attb);
    gemm_bt_kernel<64,64,64,3,true,true><<<dim3(Mrows/64, Cc/64), 256, 0, stream>>>(
        attb, HD, HD, jfb, Cc, Cc, jfb, Cc, Cc, fbt, KFUSE, h1b, Cc, &stats[0]);

    // ---- layer 1 ----
    knn_kernel<<<Bb, 64, 0, stream>>>(crd, 4, nbr1);
    gemm_bt_kernel<128,128,64,1,false,true><<<dim3(Mrows/128, QKVN/128), 256, 0, stream>>>(
        h1b, Cc, Cc, h1b, Cc, 0, h1b, Cc, 0, wqkvT + (size_t)QKVN*Cc, Cc, QKVb, QKVN, nullptr);
    attn_kernel<<<Mrows*4, 64, 0, stream>>>(QKVb, nbr1, attb);
    gemm_bt_kernel<64,64,64,3,true,false><<<dim3(Mrows/64, Cc/64), 256, 0, stream>>>(
        attb, HD, HD, h1b, Cc, Cc, jfb, Cc, Cc, fbt + (size_t)Cc*KFUSE, KFUSE, h2f, Cc, &stats[1]);

    // ---- final ----
    final_kernel<<<Mrows, 64, 0, stream>>>(h2f, fcw, fcb, stats, out);
}

// Round 9
// 238.109 us; speedup vs baseline: 1.8906x; 1.1707x over previous
//
#include <hip/hip_runtime.h>
#include <hip/hip_bf16.h>
#include <math.h>
#include <type_traits>

namespace {
constexpr int Bb = 256, Jj = 21, Cc = 256, Hh = 8, Dd = 256;
constexpr int Mrows = Bb * Jj;      // 5376
constexpr int HD    = Hh * Dd;      // 2048
constexpr int QKVN  = 3 * HD;       // 6144
constexpr int KNN   = 8;
constexpr int KFUSE = HD + Cc + Cc; // 2560

// ---- workspace byte offsets ----
// attb aliases the T region: T dead after precise_kernel, attn runs later.
constexpr size_t OFF_QKV   = 0;                                   // bf16 5376x6144
constexpr size_t OFF_T     = OFF_QKV   + (size_t)Mrows*QKVN*2;    // f32  5376x2048
constexpr size_t OFF_ATT   = OFF_T;                               // bf16 5376x2048 (alias)
constexpr size_t OFF_GT    = OFF_T     + (size_t)Mrows*HD*4;      // f16  2048x768
constexpr size_t OFF_JFB   = OFF_GT    + (size_t)HD*768*2;        // bf16 5376x256
constexpr size_t OFF_JFH   = OFF_JFB   + (size_t)Mrows*Cc*2;      // f16  5376x256
constexpr size_t OFF_JFL   = OFF_JFH   + (size_t)Mrows*Cc*2;      // f16  5376x256
constexpr size_t OFF_JFD   = OFF_JFL   + (size_t)Mrows*Cc*2;      // f16  5376x256
constexpr size_t OFF_H1B   = OFF_JFD   + (size_t)Mrows*Cc*2;      // bf16 5376x256
constexpr size_t OFF_H2F   = OFF_H1B   + (size_t)Mrows*Cc*2;      // f32  5376x256
constexpr size_t OFF_WQKVT = OFF_H2F   + (size_t)Mrows*Cc*4;      // bf16 2x6144x256
constexpr size_t OFF_FBT   = OFF_WQKVT + (size_t)2*QKVN*Cc*2;     // bf16 2x256x2560
constexpr size_t OFF_WVP   = OFF_FBT   + (size_t)2*Cc*KFUSE*2;    // f32  256x24
constexpr size_t OFF_VPROJ = OFF_WVP   + (size_t)Cc*24*4;         // f32  5376x24
constexpr size_t OFF_WSUM  = OFF_VPROJ + (size_t)Mrows*24*4;      // f32  256x4
constexpr size_t OFF_CRD   = OFF_WSUM  + (size_t)Cc*4*4;          // f32  5376x4
constexpr size_t OFF_NBR0  = OFF_CRD   + (size_t)Mrows*4*4;       // int  5376x8
constexpr size_t OFF_NBR1  = OFF_NBR0  + (size_t)Mrows*KNN*4;
constexpr size_t OFF_STAT  = OFF_NBR1  + (size_t)Mrows*KNN*4;     // 2 f32
} // namespace

typedef short short8 __attribute__((ext_vector_type(8)));
typedef _Float16 half8 __attribute__((ext_vector_type(8)));
typedef _Float16 half4v __attribute__((ext_vector_type(4)));
typedef unsigned short u16x8 __attribute__((ext_vector_type(8)));
typedef float f32x4 __attribute__((ext_vector_type(4)));

__device__ __forceinline__ unsigned short f2bf(float x) {
    unsigned int u = __float_as_uint(x);
    u = u + 0x7fffu + ((u >> 16) & 1u);            // round-to-nearest-even
    return (unsigned short)(u >> 16);
}
__device__ __forceinline__ float bf2f(unsigned short b) {
    return __uint_as_float(((unsigned int)b) << 16);
}

// ---------------------------------------------------------------------------
// kNN body: exact stable-argsort ranks 1..8 by (d2, index). Works with >=64
// threads (extra threads idle through the barrier).
__device__ __forceinline__ void knn_body(int b, const float* __restrict__ src,
                                         int ld, int* __restrict__ nbr,
                                         float (*cs)[3]) {
    int t = threadIdx.x;
    if (t < Jj) {
        const float* p = src + (size_t)(b * Jj + t) * ld;
        cs[t][0] = p[0]; cs[t][1] = p[1]; cs[t][2] = p[2];
    }
    __syncthreads();
    if (t < Jj) {
        float x = cs[t][0], y = cs[t][1], z = cs[t][2];
        float d2[Jj];
        #pragma unroll
        for (int jj = 0; jj < Jj; ++jj) {
            float dx = x - cs[jj][0], dy = y - cs[jj][1], dz = z - cs[jj][2];
            d2[jj] = dx*dx + dy*dy + dz*dz;
        }
        unsigned int used = 0u;
        int out_base = (b * Jj + t) * KNN;
        #pragma unroll
        for (int r = 0; r <= KNN; ++r) {
            int best = -1; float bd = INFINITY;
            #pragma unroll
            for (int jj = 0; jj < Jj; ++jj)
                if (!((used >> jj) & 1u) && d2[jj] < bd) { bd = d2[jj]; best = jj; }
            used |= (1u << best);
            if (r > 0) nbr[out_base + r - 1] = best;
        }
    }
}

// ---------------------------------------------------------------------------
// MEGA-PREP: one launch for all input-only work.
// blocks [0,4353): weight transposes (+wsum/stats at 4352)
// [4353,5697): cvt_split; [5697,5825): g_gemm->GT; [5825,5833): wvp;
// [5833,6089): knn layer-0.
__global__ __launch_bounds__(256)
void mega_prep_kernel(const float* __restrict__ jf,
                      const float* __restrict__ wq, const float* __restrict__ wk,
                      const float* __restrict__ wv, const float* __restrict__ wp,
                      const float* __restrict__ wsw, const float* __restrict__ wsk,
                      unsigned short* __restrict__ wqkvT,
                      unsigned short* __restrict__ fbt, float* __restrict__ stats,
                      float* __restrict__ wsum,
                      unsigned short* __restrict__ jfb, _Float16* __restrict__ jfh,
                      _Float16* __restrict__ jfl, _Float16* __restrict__ jfd,
                      _Float16* __restrict__ GT, float* __restrict__ Wvp2,
                      int* __restrict__ nbr0) {
    __shared__ __align__(16) char sm[17408];
    int bid = blockIdx.x;
    int tidx = threadIdx.x;

    if (bid < 4352) {                      // ---- weight transposes ----
        const float* src; unsigned short* dst;
        int ldin, ldout, tilesX, tile;
        constexpr size_t CH = (size_t)Cc * HD;
        if (bid < 3072) {
            int op = bid >> 9; tile = bid & 511; tilesX = 64;
            ldin = HD; ldout = Cc;
            const float* s3[3] = {wq, wk, wv};
            src = s3[op % 3] + (size_t)(op / 3) * CH;
            dst = wqkvT + (size_t)(op % 3) * HD * Cc + (size_t)(op / 3) * QKVN * Cc;
        } else if (bid < 4096) {
            int op = (bid - 3072) >> 9; tile = (bid - 3072) & 511; tilesX = 8;
            ldin = Cc; ldout = KFUSE;
            src = wp + (size_t)op * HD * Cc;
            dst = fbt + (size_t)op * Cc * KFUSE;
        } else {
            int q = bid - 4096; int op = q >> 6; tile = q & 63; tilesX = 8;
            ldin = Cc; ldout = KFUSE;
            const float* s4[4] = {wsw, wsw + (size_t)Cc * Cc, wsk, wsk};
            src = s4[op];
            dst = fbt + (size_t)(op & 1) * Cc * KFUSE + HD + (size_t)(op >> 1) * Cc;
        }
        int bx = tile % tilesX, by = tile / tilesX;
        int n0 = bx * 32, k0 = by * 32;
        float (*t)[33] = (float(*)[33])sm;
        int r = tidx >> 3, c4 = (tidx & 7) * 4;
        float4 v = *(const float4*)&src[(size_t)(k0 + r) * ldin + n0 + c4];
        t[r][c4+0] = v.x; t[r][c4+1] = v.y; t[r][c4+2] = v.z; t[r][c4+3] = v.w;
        __syncthreads();
        ushort4 o;
        o.x = f2bf(t[c4+0][r]); o.y = f2bf(t[c4+1][r]);
        o.z = f2bf(t[c4+2][r]); o.w = f2bf(t[c4+3][r]);
        *(ushort4*)&dst[(size_t)(n0 + r) * ldout + k0 + c4] = o;
    } else if (bid == 4352) {              // ---- wsum + stats zero ----
        int e = tidx;
        float4 o;
        o.x = wsw[(size_t)e*Dd + 0] + wsk[(size_t)e*Dd + 0];
        o.y = wsw[(size_t)e*Dd + 1] + wsk[(size_t)e*Dd + 1];
        o.z = wsw[(size_t)e*Dd + 2] + wsk[(size_t)e*Dd + 2];
        o.w = 0.0f;
        *(float4*)&wsum[e*4] = o;
        if (e < 2) stats[e] = 0.0f;
    } else if (bid < 5697) {               // ---- cvt_split ----
        int i = (bid - 4353) * 256 + tidx;
        float4 v = ((const float4*)jf)[i];
        float x[4] = {v.x, v.y, v.z, v.w};
        ushort4 ob; half4v oh, ol, od;
        #pragma unroll
        for (int u = 0; u < 4; ++u) {
            ((unsigned short*)&ob)[u] = f2bf(x[u]);
            _Float16 h = (_Float16)x[u];
            oh[u] = h;
            ol[u] = (_Float16)((x[u] - (float)h) * 16.0f);
            od[u] = (_Float16)(x[u] * 0.0078125f);   // /128
        }
        ((ushort4*)jfb)[i] = ob;
        ((half4v*)jfh)[i] = oh;
        ((half4v*)jfl)[i] = ol;
        ((half4v*)jfd)[i] = od;
    } else if (bid < 5825) {               // ---- g_gemm -> GT (fp16-split) ----
        int q = bid - 5697;
        int h = q >> 4, rem = q & 15;
        int m0 = (rem >> 2) * 64, n0 = (rem & 3) * 64;
        float (*As)[68] = (float(*)[68])sm;
        float (*Ws)[68] = (float(*)[68])(sm + 8704);
        int ty = tidx >> 4, tx = tidx & 15;
        float acc[4][4] = {};
        for (int kb = 0; kb < 256; kb += 32) {
            #pragma unroll
            for (int it = 0; it < 2; ++it) {
                int c = tidx + it * 256;
                int row = c >> 3, col = (c & 7) * 4;
                float4 v = *(const float4*)&wq[(size_t)(m0 + row)*HD + h*256 + kb + col];
                float4 u = *(const float4*)&wk[(size_t)(n0 + row)*HD + h*256 + kb + col];
                As[col+0][row] = v.x; As[col+1][row] = v.y;
                As[col+2][row] = v.z; As[col+3][row] = v.w;
                Ws[col+0][row] = u.x; Ws[col+1][row] = u.y;
                Ws[col+2][row] = u.z; Ws[col+3][row] = u.w;
            }
            __syncthreads();
            #pragma unroll
            for (int kk = 0; kk < 32; ++kk) {
                float4 a = *(const float4*)&As[kk][ty*4];
                float4 b = *(const float4*)&Ws[kk][tx*4];
                float av[4] = {a.x, a.y, a.z, a.w};
                float bv[4] = {b.x, b.y, b.z, b.w};
                #pragma unroll
                for (int i = 0; i < 4; ++i)
                    #pragma unroll
                    for (int j = 0; j < 4; ++j)
                        acc[i][j] += av[i] * bv[j];
            }
            __syncthreads();
        }
        #pragma unroll
        for (int j = 0; j < 4; ++j) {
            int n = h*256 + n0 + tx*4 + j;
            half4v hi, hs, lo;
            #pragma unroll
            for (int i = 0; i < 4; ++i) {
                float g = acc[i][j];
                _Float16 gh = (_Float16)g;
                hi[i] = gh;
                hs[i] = (_Float16)(g * 0.0625f);
                lo[i] = (_Float16)((g - (float)gh) * 128.0f);
            }
            _Float16* base = &GT[(size_t)n*768 + m0 + ty*4];
            *(half4v*)(base)       = hi;
            *(half4v*)(base + 256) = hs;
            *(half4v*)(base + 512) = lo;
        }
    } else if (bid < 5833) {               // ---- wvp ----
        int h = bid - 5825;
        float (*wpc)[3] = (float(*)[3])sm;
        int t = tidx;
        const float* p = &wp[(size_t)(h*256 + t) * Cc];
        wpc[t][0] = p[0]; wpc[t][1] = p[1]; wpc[t][2] = p[2];
        __syncthreads();
        const float* vr = &wv[(size_t)t*HD + h*256];
        float a0=0, a1=0, a2=0;
        for (int d = 0; d < 256; ++d) {
            float v = vr[d];
            a0 += v*wpc[d][0]; a1 += v*wpc[d][1]; a2 += v*wpc[d][2];
        }
        float* o = &Wvp2[(size_t)t*24 + h*3];
        o[0]=a0; o[1]=a1; o[2]=a2;
    } else {                               // ---- knn layer 0 ----
        knn_body(bid - 5833, jf, Cc, nbr0, (float(*)[3])sm);
    }
}

// ---------------------------------------------------------------------------
// 16-bit MFMA GEMM core (bf16 or f16), B^T input, segmented A along K,
// fp32 accum, XOR-swizzled LDS (source-permuted / dest-linear / read-swizzled).
template<int BM, int BN, int BK, int NSEG, bool RELU_STATS, bool OUT_BF16, bool F16>
__device__ __forceinline__
void gemm_core(unsigned short* As, unsigned short* Bs, float* red,
               int bm, int bn,
               const unsigned short* __restrict__ A0, int lda0, int klen0,
               const unsigned short* __restrict__ A1, int lda1, int klen1,
               const unsigned short* __restrict__ A2, int lda2, int klen2,
               const unsigned short* __restrict__ Bt, int ldb,
               void* __restrict__ Cv, int ldc, float* __restrict__ stat) {
    constexpr int WM = BM/2, WN = BN/2;
    constexpr int MW = WM/16, NW = WN/16, KW = BK/32;
    constexpr int CHUNKA = BM*BK/8;
    constexpr int CHUNKB = BN*BK/8;
    constexpr int KB8 = BK/8;
    constexpr int SWZ = KB8 - 1;
    using frag = std::conditional_t<F16, half8, short8>;

    int tid = threadIdx.x;
    int wid = tid >> 6, lane = tid & 63;
    int wr = wid >> 1, wc = wid & 1;

    f32x4 acc[MW][NW];
    #pragma unroll
    for (int m = 0; m < MW; ++m)
        #pragma unroll
        for (int n = 0; n < NW; ++n)
            acc[m][n] = (f32x4){0.f, 0.f, 0.f, 0.f};

    const unsigned short* Aseg[3] = {A0, A1, A2};
    const int ldas[3] = {lda0, lda1, lda2};
    const int klens[3] = {klen0, klen1, klen2};

    int kglob = 0;
    for (int seg = 0; seg < NSEG; ++seg) {
        const unsigned short* A = Aseg[seg];
        const int lda = ldas[seg];
        const int klen = klens[seg];
        for (int k0 = 0; k0 < klen; k0 += BK) {
            #pragma unroll
            for (int it = 0; it < CHUNKA/256; ++it) {
                int c = tid + it*256;
                int row = c / KB8;
                int kp = (c % KB8) ^ (row & SWZ);
                __builtin_amdgcn_global_load_lds(
                    (const __attribute__((address_space(1))) unsigned int*)
                        (A + (size_t)(bm + row)*lda + k0 + kp*8),
                    (__attribute__((address_space(3))) unsigned int*)(As + c*8),
                    16, 0, 0);
            }
            #pragma unroll
            for (int it = 0; it < CHUNKB/256; ++it) {
                int c = tid + it*256;
                int row = c / KB8;
                int kp = (c % KB8) ^ (row & SWZ);
                __builtin_amdgcn_global_load_lds(
                    (const __attribute__((address_space(1))) unsigned int*)
                        (Bt + (size_t)(bn + row)*ldb + kglob + k0 + kp*8),
                    (__attribute__((address_space(3))) unsigned int*)(Bs + c*8),
                    16, 0, 0);
            }
            __syncthreads();
            #pragma unroll
            for (int kp = 0; kp < KW; ++kp) {
                frag af[MW], bf[NW];
                int cbase = kp*4 + (lane >> 4);
                #pragma unroll
                for (int m = 0; m < MW; ++m) {
                    int r = wr*WM + m*16 + (lane & 15);
                    af[m] = *(const frag*)&As[r*BK + ((cbase ^ (r & SWZ))*8)];
                }
                #pragma unroll
                for (int n = 0; n < NW; ++n) {
                    int r = wc*WN + n*16 + (lane & 15);
                    bf[n] = *(const frag*)&Bs[r*BK + ((cbase ^ (r & SWZ))*8)];
                }
                #pragma unroll
                for (int m = 0; m < MW; ++m)
                    #pragma unroll
                    for (int n = 0; n < NW; ++n) {
                        if constexpr (F16)
                            acc[m][n] = __builtin_amdgcn_mfma_f32_16x16x32_f16(
                                af[m], bf[n], acc[m][n], 0, 0, 0);
                        else
                            acc[m][n] = __builtin_amdgcn_mfma_f32_16x16x32_bf16(
                                af[m], bf[n], acc[m][n], 0, 0, 0);
                    }
            }
            __syncthreads();
        }
        kglob += klen;
    }

    int cr = (lane >> 4)*4, cc = lane & 15;
    float bsum = 0.0f;
    #pragma unroll
    for (int m = 0; m < MW; ++m)
        #pragma unroll
        for (int n = 0; n < NW; ++n)
            #pragma unroll
            for (int j = 0; j < 4; ++j) {
                float v = acc[m][n][j];
                if (RELU_STATS) { v = fmaxf(v, 0.0f); bsum += v; }
                size_t row = bm + wr*WM + m*16 + cr + j;
                size_t col = bn + wc*WN + n*16 + cc;
                if (OUT_BF16) ((unsigned short*)Cv)[row*ldc + col] = f2bf(v);
                else          ((float*)Cv)[row*ldc + col] = v;
            }
    if (RELU_STATS) {
        #pragma unroll
        for (int sft = 1; sft < 64; sft <<= 1) bsum += __shfl_xor(bsum, sft);
        if (lane == 0) red[wid] = bsum;
        __syncthreads();
        if (tid == 0) atomicAdd(stat, red[0] + red[1] + red[2] + red[3]);
    }
}

// ---------------------------------------------------------------------------
// COMBO: y<48 -> layer-0 QKV gemm (bf16); y in [48,64) -> fp16-split T-gemm;
// y in [64,80) -> vproj. All independent.
__global__ __launch_bounds__(256)
void combo_kernel(const unsigned short* __restrict__ jfb,
                  const unsigned short* __restrict__ wqkvT,
                  unsigned short* __restrict__ QKVb,
                  const _Float16* __restrict__ jfh, const _Float16* __restrict__ jfl,
                  const _Float16* __restrict__ jfd, const _Float16* __restrict__ GT,
                  float* __restrict__ Tm,
                  const float* __restrict__ jf, const float* __restrict__ Wvp2,
                  float* __restrict__ vproj) {
    __shared__ __align__(16) char smem[32784];
    unsigned short* As = (unsigned short*)smem;
    unsigned short* Bs = (unsigned short*)(smem + 16384);
    float* red = (float*)(smem + 32768);
    int x = blockIdx.x, y = blockIdx.y;
    if (y < 48) {
        gemm_core<128,128,64,1,false,true,false>(As, Bs, red, x*128, y*128,
            jfb, Cc, Cc, jfb, Cc, 0, jfb, Cc, 0, wqkvT, Cc, QKVb, QKVN, nullptr);
    } else if (y < 64) {
        gemm_core<128,128,64,3,false,false,true>(As, Bs, red, x*128, (y-48)*128,
            (const unsigned short*)jfh, Cc, Cc, (const unsigned short*)jfl, Cc, Cc,
            (const unsigned short*)jfd, Cc, Cc, (const unsigned short*)GT, 768,
            Tm, HD, nullptr);
    } else {
        // vproj: 8 rows/block, block id q in [0,672)
        int q = (y - 64) * 42 + x;
        float (*hr)[256] = (float(*)[256])smem;
        float* wl = (float*)(smem + 8192);
        int t = threadIdx.x;
        int j0 = q * 8;
        #pragma unroll
        for (int i = 0; i < 6; ++i)
            *(float4*)&wl[t*4 + i*1024] = *(const float4*)&Wvp2[t*4 + i*1024];
        {
            int r = t >> 5, c = (t & 31) * 8;
            const float* src = &jf[(size_t)(j0 + r)*Cc + c];
            *(float4*)&hr[r][c]   = *(const float4*)src;
            *(float4*)&hr[r][c+4] = *(const float4*)(src + 4);
        }
        __syncthreads();
        int r = t >> 5, o = t & 31;
        if (o < 24) {
            float a = 0.0f;
            for (int e = 0; e < 256; ++e) a += hr[r][e] * wl[e*24 + o];
            vproj[(size_t)(j0 + r)*24 + o] = a;
        }
    }
}

// ---------------------------------------------------------------------------
// standalone MFMA gemm (for layer-1 QKV)
template<int BM, int BN, int BK, int NSEG, bool RELU_STATS, bool OUT_BF16, bool F16 = false>
__global__ __launch_bounds__(256)
void gemm_bt_kernel(const unsigned short* __restrict__ A0, int lda0, int klen0,
                    const unsigned short* __restrict__ A1, int lda1, int klen1,
                    const unsigned short* __restrict__ A2, int lda2, int klen2,
                    const unsigned short* __restrict__ Bt, int ldb,
                    void* __restrict__ Cv, int ldc, float* __restrict__ stat) {
    __shared__ __align__(16) unsigned short As[BM*BK];
    __shared__ __align__(16) unsigned short Bs[BN*BK];
    __shared__ float red[4];
    gemm_core<BM,BN,BK,NSEG,RELU_STATS,OUT_BF16,F16>(
        As, Bs, red, blockIdx.x*BM, blockIdx.y*BN,
        A0, lda0, klen0, A1, lda1, klen1, A2, lda2, klen2,
        Bt, ldb, Cv, ldc, stat);
}

// ---------------------------------------------------------------------------
// fused epilogue gemm (+ optional layer-1 kNN in extra y-blocks)
template<bool OUT_BF16, bool DO_KNN>
__global__ __launch_bounds__(256)
void fused_kernel(const unsigned short* __restrict__ att,
                  const unsigned short* __restrict__ hseg,
                  const unsigned short* __restrict__ h0seg,
                  const unsigned short* __restrict__ fbtL,
                  void* __restrict__ Cv, float* __restrict__ stat,
                  const float* __restrict__ crd, int* __restrict__ nbr1) {
    __shared__ __align__(16) char smem[16400];
    if (DO_KNN && blockIdx.y >= 4) {
        int b = (blockIdx.y - 4) * 84 + blockIdx.x;
        if (b < Bb) knn_body(b, crd, 4, nbr1, (float(*)[3])smem);
        return;
    }
    unsigned short* As = (unsigned short*)smem;
    unsigned short* Bs = (unsigned short*)(smem + 8192);
    float* red = (float*)(smem + 16384);
    gemm_core<64,64,64,3,true,OUT_BF16,false>(
        As, Bs, red, blockIdx.x*64, blockIdx.y*64,
        att, HD, HD, hseg, Cc, Cc, h0seg, Cc, Cc,
        fbtL, KFUSE, Cv, Cc, stat);
}

// ---------------------------------------------------------------------------
// precise layer-0 coords
__global__ __launch_bounds__(64)
void precise_kernel(const float* __restrict__ T, const float* __restrict__ h0,
                    const int* __restrict__ nbr, const float* __restrict__ vproj,
                    const float* __restrict__ wsum, float* __restrict__ crd) {
    int i = blockIdx.x;
    int b = i / Jj;
    int l = threadIdx.x;
    __shared__ float Ts[8][260];
    __shared__ float nb[8][260];
    __shared__ float hi[256];
    #pragma unroll
    for (int u = 0; u < 8; ++u) {
        int idx = u*64 + l;
        float4 v = *(const float4*)&T[(size_t)i*HD + idx*4];
        int hh = idx >> 6, dd = (idx & 63) * 4;
        *(float4*)&Ts[hh][dd] = v;
    }
    *(float4*)&hi[l*4] = *(const float4*)&h0[(size_t)i*Cc + l*4];
    int kq = l >> 3, s = l & 7;
    int njs = nbr[i*KNN + kq];
    const float* nrow = &h0[(size_t)(b*Jj + njs)*Cc];
    #pragma unroll
    for (int u = 0; u < 8; ++u)
        *(float4*)&nb[kq][(s*8+u)*4] = *(const float4*)&nrow[(s*8+u)*4];
    __syncthreads();

    int k = l >> 3, h = l & 7;
    float sacc = 0;
    #pragma unroll 8
    for (int d = 0; d < 256; d += 4) {
        float4 tv = *(const float4*)&Ts[h][d];
        float4 nv = *(const float4*)&nb[k][d];
        sacc += tv.x*nv.x + tv.y*nv.y + tv.z*nv.z + tv.w*nv.w;
    }
    float sc = sacc * 0.0625f;
    sc = (sc >= 0.0f) ? sc : 0.2f * sc;
    float m = sc;
    m = fmaxf(m, __shfl_xor(m, 8));
    m = fmaxf(m, __shfl_xor(m, 16));
    m = fmaxf(m, __shfl_xor(m, 32));
    float e = expf(sc - m);
    float den = e;
    den += __shfl_xor(den, 8); den += __shfl_xor(den, 16); den += __shfl_xor(den, 32);
    float w = e / den;

    int njk = nbr[i*KNN + k];
    const float* vp = &vproj[(size_t)(b*Jj + njk)*24 + h*3];
    float t0 = w * vp[0], t1 = w * vp[1], t2 = w * vp[2];
    #pragma unroll
    for (int u = 0; u < 4; ++u) {
        int e4 = l*4 + u;
        float hv = hi[e4];
        float4 wv = *(const float4*)&wsum[e4*4];
        t0 += hv * wv.x; t1 += hv * wv.y; t2 += hv * wv.z;
    }
    #pragma unroll
    for (int sft = 1; sft < 64; sft <<= 1) {
        t0 += __shfl_xor(t0, sft); t1 += __shfl_xor(t1, sft); t2 += __shfl_xor(t2, sft);
    }
    if (l == 0) {
        crd[i*4+0] = fmaxf(t0, 0.0f);
        crd[i*4+1] = fmaxf(t1, 0.0f);
        crd[i*4+2] = fmaxf(t2, 0.0f);
        crd[i*4+3] = 0.0f;
    }
}

// ---------------------------------------------------------------------------
// attention: one wave per (row, head-pair); 32 lanes per head, ushort8 loads.
__global__ __launch_bounds__(64)
void attn_kernel(const unsigned short* __restrict__ QKV,
                 const int* __restrict__ nbr, unsigned short* __restrict__ att) {
    int gid = blockIdx.x;
    int hp = gid & 3, row = gid >> 2, b = row / Jj;
    int lane = threadIdx.x;
    int h = hp*2 + (lane >> 5);
    int d0 = (lane & 31) * 8;

    u16x8 qu = *(const u16x8*)&QKV[(size_t)row*QKVN + h*Dd + d0];
    float qf[8];
    #pragma unroll
    for (int i = 0; i < 8; ++i) qf[i] = bf2f(qu[i]);
    const int* np_ = nbr + row * KNN;

    float sc[KNN]; int nb[KNN];
    #pragma unroll
    for (int k = 0; k < KNN; ++k) {
        int n = np_[k]; nb[k] = n;
        u16x8 ku = *(const u16x8*)&QKV[(size_t)(b*Jj + n)*QKVN + HD + h*Dd + d0];
        float p = 0;
        #pragma unroll
        for (int i = 0; i < 8; ++i) p += qf[i] * bf2f(ku[i]);
        #pragma unroll
        for (int s = 1; s < 32; s <<= 1) p += __shfl_xor(p, s);
        sc[k] = p;
    }
    float mx = -INFINITY;
    #pragma unroll
    for (int k = 0; k < KNN; ++k) {
        float s = sc[k] * 0.0625f;
        s = (s >= 0.0f) ? s : 0.2f * s;
        sc[k] = s; mx = fmaxf(mx, s);
    }
    float den = 0.0f;
    #pragma unroll
    for (int k = 0; k < KNN; ++k) { sc[k] = expf(sc[k] - mx); den += sc[k]; }
    float inv = 1.0f / den;
    float o[8] = {};
    #pragma unroll
    for (int k = 0; k < KNN; ++k) {
        u16x8 vu = *(const u16x8*)&QKV[(size_t)(b*Jj + nb[k])*QKVN + 2*HD + h*Dd + d0];
        float w = sc[k] * inv;
        #pragma unroll
        for (int i = 0; i < 8; ++i) o[i] += w * bf2f(vu[i]);
    }
    u16x8 ou;
    #pragma unroll
    for (int i = 0; i < 8; ++i) ou[i] = f2bf(o[i]);
    *(u16x8*)&att[(size_t)row*HD + h*Dd + d0] = ou;
}

// ---------------------------------------------------------------------------
__global__ __launch_bounds__(64)
void final_kernel(const float* __restrict__ h, const float* __restrict__ fcw,
                  const float* __restrict__ fcb, const float* __restrict__ stats,
                  float* __restrict__ out) {
    int row = blockIdx.x, lane = threadIdx.x;
    const float4 hv = *(const float4*)(h + (size_t)row*Cc + lane*4);
    float a0=0, a1=0, a2=0;
    const float hx[4] = {hv.x, hv.y, hv.z, hv.w};
    #pragma unroll
    for (int i = 0; i < 4; ++i) {
        int c = lane*4 + i;
        a0 += hx[i]*fcw[c*3+0]; a1 += hx[i]*fcw[c*3+1]; a2 += hx[i]*fcw[c*3+2];
    }
    #pragma unroll
    for (int s = 32; s > 0; s >>= 1) {
        a0 += __shfl_xor(a0, s); a1 += __shfl_xor(a1, s); a2 += __shfl_xor(a2, s);
    }
    if (lane == 0) {
        out[row*3+0] = a0 + fcb[0];
        out[row*3+1] = a1 + fcb[1];
        out[row*3+2] = a2 + fcb[2];
        if (row == 0)
            out[(size_t)Mrows*3] =
                (stats[0] + stats[1]) * (0.5f / ((float)Mrows * (float)Cc));
    }
}

// ---------------------------------------------------------------------------
extern "C" void kernel_launch(void* const* d_in, const int* in_sizes, int n_in,
                              void* d_out, int out_size, void* d_ws, size_t ws_size,
                              hipStream_t stream) {
    (void)in_sizes; (void)n_in; (void)out_size; (void)ws_size;
    const float* jf     = (const float*)d_in[0];
    const float* wq     = (const float*)d_in[1];
    const float* wk     = (const float*)d_in[2];
    const float* wv     = (const float*)d_in[3];
    const float* wp     = (const float*)d_in[4];
    const float* wsw    = (const float*)d_in[5];
    const float* wskip0 = (const float*)d_in[6];
    const float* fcw    = (const float*)d_in[7];
    const float* fcb    = (const float*)d_in[8];
    float* out = (float*)d_out;

    char* wsb = (char*)d_ws;
    unsigned short* QKVb  = (unsigned short*)(wsb + OFF_QKV);
    float*          Tm    = (float*)(wsb + OFF_T);
    unsigned short* attb  = (unsigned short*)(wsb + OFF_ATT);   // aliases T
    _Float16*       GT    = (_Float16*)(wsb + OFF_GT);
    unsigned short* jfb   = (unsigned short*)(wsb + OFF_JFB);
    _Float16*       jfh   = (_Float16*)(wsb + OFF_JFH);
    _Float16*       jfl   = (_Float16*)(wsb + OFF_JFL);
    _Float16*       jfd   = (_Float16*)(wsb + OFF_JFD);
    unsigned short* h1b   = (unsigned short*)(wsb + OFF_H1B);
    float*          h2f   = (float*)(wsb + OFF_H2F);
    unsigned short* wqkvT = (unsigned short*)(wsb + OFF_WQKVT);
    unsigned short* fbt   = (unsigned short*)(wsb + OFF_FBT);
    float*          Wvp   = (float*)(wsb + OFF_WVP);
    float*          vproj = (float*)(wsb + OFF_VPROJ);
    float*          wsum  = (float*)(wsb + OFF_WSUM);
    float*          crd   = (float*)(wsb + OFF_CRD);
    int*            nbr0  = (int*)(wsb + OFF_NBR0);
    int*            nbr1  = (int*)(wsb + OFF_NBR1);
    float*          stats = (float*)(wsb + OFF_STAT);

    // 1. all input-only prep in one launch
    mega_prep_kernel<<<6089, 256, 0, stream>>>(jf, wq, wk, wv, wp, wsw, wskip0,
                                               wqkvT, fbt, stats, wsum,
                                               jfb, jfh, jfl, jfd, GT, Wvp, nbr0);
    // 2. layer-0 QKV gemm + fp16-split T-gemm + vproj in one launch
    combo_kernel<<<dim3(42, 80), 256, 0, stream>>>(jfb, wqkvT, QKVb,
                                                   jfh, jfl, jfd, GT, Tm,
                                                   jf, Wvp, vproj);
    // 3. precise layer-0 coords (consumes Tm; attb may overwrite it after)
    precise_kernel<<<Mrows, 64, 0, stream>>>(Tm, jf, nbr0, vproj, wsum, crd);
    // 4. layer-0 attention
    attn_kernel<<<Mrows*4, 64, 0, stream>>>(QKVb, nbr0, attb);
    // 5. layer-0 fused output gemm + layer-1 kNN
    fused_kernel<true, true><<<dim3(84, 8), 256, 0, stream>>>(
        attb, jfb, jfb, fbt, h1b, &stats[0], crd, nbr1);
    // 6. layer-1 QKV gemm
    gemm_bt_kernel<128,128,64,1,false,true><<<dim3(Mrows/128, QKVN/128), 256, 0, stream>>>(
        h1b, Cc, Cc, h1b, Cc, 0, h1b, Cc, 0, wqkvT + (size_t)QKVN*Cc, Cc, QKVb, QKVN, nullptr);
    // 7. layer-1 attention
    attn_kernel<<<Mrows*4, 64, 0, stream>>>(QKVb, nbr1, attb);
    // 8. layer-1 fused output gemm
    fused_kernel<false, false><<<dim3(84, 4), 256, 0, stream>>>(
        attb, h1b, jfb, fbt + (size_t)Cc*KFUSE, h2f, &stats[1], nullptr, nullptr);
    // 9. final
    final_kernel<<<Mrows, 64, 0, stream>>>(h2f, fcw, fcb, stats, out);
}